// Round 3
// baseline (2074.890 us; speedup 1.0000x reference)
//
#include <hip/hip_runtime.h>
#include <hip/hip_fp16.h>
#include <math.h>

// ---------------------------------------------------------------------------
// GTR_50139448214076: 3x TransformerConv GNN + BN/ELU + mean-pool + MLP
// fp32 everywhere except edge features (fp16, CSR-ordered).
// Adaptive workspace: fixed = OUT/K/V slots + EF(fp16) + CSR (~209 MB);
// per-dst tensors (Q, QWE, skip, SE) processed in node chunks sized from
// ws_size. If it cannot fit, leak ws_size via d_out (absmax ~= ws_MB).
// Identity: q.(k+e@we) = q.k + e.(q@weT);  sum w*(v+e@we) = sum w*v + (sum w*e)@we
// ---------------------------------------------------------------------------

__device__ __forceinline__ float4 ld4(const float* p){ return *reinterpret_cast<const float4*>(p); }

// ---------------- utility ----------------
__global__ void zero_kernel(int* __restrict__ p, int n){
  int i = blockIdx.x*blockDim.x + threadIdx.x;
  if (i < n) p[i] = 0;
}

__global__ void leak_kernel(float* __restrict__ out, int n, float val){
  int i = blockIdx.x*blockDim.x + threadIdx.x;
  if (i < n) out[i] = val;
}

// ---------------- CSR build ----------------
__global__ void hist_kernel(const int* __restrict__ dst, int* __restrict__ deg, int E){
  int i = blockIdx.x*blockDim.x + threadIdx.x;
  if (i < E) atomicAdd(&deg[dst[i]], 1);
}

__global__ __launch_bounds__(1024)
void scan_kernel(const int* __restrict__ deg, int* __restrict__ rowptr, int n){
  __shared__ int buf[1024];
  __shared__ int sbase;
  int tid = threadIdx.x;
  if (tid == 0){ sbase = 0; rowptr[0] = 0; }
  __syncthreads();
  for (int start = 0; start < n; start += 4096){
    int i0 = start + tid*4;
    int a0 = (i0+0<n)?deg[i0+0]:0;
    int a1 = (i0+1<n)?deg[i0+1]:0;
    int a2 = (i0+2<n)?deg[i0+2]:0;
    int a3 = (i0+3<n)?deg[i0+3]:0;
    int s = a0+a1+a2+a3;
    int v = s;
    buf[tid] = v;
    __syncthreads();
    for (int off=1; off<1024; off<<=1){
      int t = (tid >= off) ? buf[tid-off] : 0;
      __syncthreads();
      v += t;
      buf[tid] = v;
      __syncthreads();
    }
    int pre = sbase + v - s;   // exclusive prefix (sbase read before its update)
    if (i0+0 < n) rowptr[i0+1] = pre + a0;
    if (i0+1 < n) rowptr[i0+2] = pre + a0 + a1;
    if (i0+2 < n) rowptr[i0+3] = pre + a0 + a1 + a2;
    if (i0+3 < n) rowptr[i0+4] = pre + s;
    __syncthreads();
    if (tid == 1023) sbase += buf[1023];
    __syncthreads();
  }
}

__global__ void scatter_kernel(const int* __restrict__ src, const int* __restrict__ dst,
                               const int* __restrict__ rowptr, int* __restrict__ cnt,
                               int* __restrict__ csr_src, int* __restrict__ csr_eid, int E){
  int i = blockIdx.x*blockDim.x + threadIdx.x;
  if (i >= E) return;
  int d = dst[i];
  int pos = rowptr[d] + atomicAdd(&cnt[d], 1);
  csr_src[pos] = src[i];
  csr_eid[pos] = i;
}

// EFh[i] = fp16(EFt[csr_eid[i]])  (edge features -> CSR order, fp16)
__global__ void gather_ef_kernel(const float* __restrict__ EFt, const int* __restrict__ csr_eid,
                                 __half* __restrict__ EFh, int E){
  int i = blockIdx.x*blockDim.x + threadIdx.x;   // over E*16 quads
  if (i >= E*16) return;
  int e = i >> 4, c4 = (i & 15) * 4;
  float4 v = ld4(&EFt[(size_t)csr_eid[e]*64 + c4]);
  __half2 lo = __floats2half2_rn(v.x, v.y);
  __half2 hi = __floats2half2_rn(v.z, v.w);
  __half2* dst2 = reinterpret_cast<__half2*>(&EFh[(size_t)e*64 + c4]);
  dst2[0] = lo; dst2[1] = hi;
}

// weT[h][c][k] = we[k][h*64+c]
__global__ void transpose_we_kernel(const float* __restrict__ we, float* __restrict__ weT,
                                    int H, int hc){
  int idx = blockIdx.x*blockDim.x + threadIdx.x;
  if (idx >= H*4096) return;
  int h = idx >> 12; int c = (idx >> 6) & 63; int k = idx & 63;
  weT[idx] = we[k*hc + h*64 + c];
}

// ---------------- generic fp32 GEMM with epilogues ----------------
// mode 0: +bias; mode 1: +bias,relu; mode 2: +ep1, BN, ELU.
__device__ __forceinline__ float bn_elu(float x, float g, float b, float m, float v){
  float s = g / sqrtf(v + 1e-5f);
  float y = (x - m) * s + b;
  return y > 0.f ? y : expm1f(y);
}

__global__ __launch_bounds__(256)
void gemm_kernel(const float* __restrict__ A, int lda, long aZ,
                 const float* __restrict__ B, int ldb, long bZ,
                 float* __restrict__ C, int ldc, long cZ,
                 const float* __restrict__ bias,
                 int M, int Nc, int K, int mode,
                 const float* __restrict__ ep1,
                 const float* __restrict__ bng, const float* __restrict__ bnb,
                 const float* __restrict__ bnm, const float* __restrict__ bnv)
{
  __shared__ float As[32][132];
  __shared__ float Bs[32][64];
  const int tid = threadIdx.x;
  const int tx = tid & 15, ty = tid >> 4;
  const int z = blockIdx.z;
  const float* Ab = A + (long)z * aZ;
  const float* Bb = B + (long)z * bZ;
  float* Cb = C + (long)z * cZ;
  const int row0 = blockIdx.x * 128;
  const int col0 = blockIdx.y * 64;

  float acc[8][4];
  #pragma unroll
  for (int i=0;i<8;i++)
    #pragma unroll
    for(int j=0;j<4;j++) acc[i][j]=0.f;

  const int am  = tid & 127;
  const int akq = tid >> 7;
  const int brow = tid >> 4;
  const int bn4 = (tid & 15) * 4;

  for (int k0 = 0; k0 < K; k0 += 32) {
    {
      int row = row0 + am;
      #pragma unroll
      for (int i = 0; i < 4; ++i) {
        int kk = 16*akq + 4*i;
        int kg = k0 + kk;
        float4 v = make_float4(0.f,0.f,0.f,0.f);
        if (row < M && kg < K) v = ld4(&Ab[(long)row * lda + kg]);
        As[kk+0][am]=v.x; As[kk+1][am]=v.y; As[kk+2][am]=v.z; As[kk+3][am]=v.w;
      }
    }
    {
      #pragma unroll
      for (int j = 0; j < 2; ++j) {
        int kb = brow + 16*j;
        int kg = k0 + kb;
        float4 v = make_float4(0.f,0.f,0.f,0.f);
        if (kg < K) v = ld4(&Bb[(long)kg * ldb + col0 + bn4]);
        *reinterpret_cast<float4*>(&Bs[kb][bn4]) = v;
      }
    }
    __syncthreads();
    #pragma unroll
    for (int kk = 0; kk < 32; ++kk) {
      float a[8], b[4];
      *reinterpret_cast<float4*>(&a[0]) = *reinterpret_cast<const float4*>(&As[kk][ty*8]);
      *reinterpret_cast<float4*>(&a[4]) = *reinterpret_cast<const float4*>(&As[kk][ty*8+4]);
      *reinterpret_cast<float4*>(&b[0]) = *reinterpret_cast<const float4*>(&Bs[kk][tx*4]);
      #pragma unroll
      for (int i=0;i<8;i++)
        #pragma unroll
        for (int j=0;j<4;j++)
          acc[i][j] = fmaf(a[i], b[j], acc[i][j]);
    }
    __syncthreads();
  }

  const int chan0 = z*64 + col0 + tx*4;
  #pragma unroll
  for (int i = 0; i < 8; ++i) {
    int row = row0 + ty*8 + i;
    if (row >= M) continue;
    long cidx = (long)row * ldc + col0 + tx*4;
    float r0=acc[i][0], r1=acc[i][1], r2=acc[i][2], r3=acc[i][3];
    if (bias){ r0+=bias[chan0]; r1+=bias[chan0+1]; r2+=bias[chan0+2]; r3+=bias[chan0+3]; }
    if (mode == 1) {
      r0=fmaxf(r0,0.f); r1=fmaxf(r1,0.f); r2=fmaxf(r2,0.f); r3=fmaxf(r3,0.f);
    } else if (mode == 2) {
      long eidx = (long)z * cZ + cidx;
      float4 a1 = ld4(&ep1[eidx]);
      r0 += a1.x; r1 += a1.y; r2 += a1.z; r3 += a1.w;
      r0 = bn_elu(r0, bng[chan0+0], bnb[chan0+0], bnm[chan0+0], bnv[chan0+0]);
      r1 = bn_elu(r1, bng[chan0+1], bnb[chan0+1], bnm[chan0+1], bnv[chan0+1]);
      r2 = bn_elu(r2, bng[chan0+2], bnb[chan0+2], bnm[chan0+2], bnv[chan0+2]);
      r3 = bn_elu(r3, bng[chan0+3], bnb[chan0+3], bnm[chan0+3], bnv[chan0+3]);
    }
    float4 out = make_float4(r0,r1,r2,r3);
    *reinterpret_cast<float4*>(&Cb[cidx]) = out;
  }
}

// ---------------- aggregation (chunked): online softmax over in-edges -------
// HC=256: wave per node (4 lanes-groups = 4 heads). HC=64: wave per 4 nodes.
// Qc/QWEc/Sc/SEc are chunk-local (row = node - n0); K/V/EF/rowptr/csr global.
template<int HC>
__global__ __launch_bounds__(256)
void agg_kernel(const int* __restrict__ rowptr, const int* __restrict__ csr_src,
                const float* __restrict__ Qc, const float* __restrict__ Kf,
                const float* __restrict__ Vf, const float* __restrict__ QWEc,
                const __half* __restrict__ EFh,
                float* __restrict__ Sc, float* __restrict__ SEc,
                int n0, int Cc)
{
  int lane = threadIdx.x & 63;
  int wid = (blockIdx.x * blockDim.x + threadIdx.x) >> 6;
  int grp = lane >> 4;
  int l16 = lane & 15;
  int loc, ch;
  if (HC == 256) { loc = wid;         ch = 4*lane; }
  else           { loc = wid*4 + grp; ch = 4*l16;  }
  if (loc >= Cc) return;
  int node = n0 + loc;

  float4 q4 = ld4(&Qc[(size_t)loc*HC + ch]);
  float4 w4 = ld4(&QWEc[(size_t)loc*HC + ch]);
  int e0 = rowptr[node], e1 = rowptr[node+1];

  float m = -INFINITY, den = 0.f;
  float avx=0.f, avy=0.f, avz=0.f, avw=0.f;
  float aex=0.f, aey=0.f, aez=0.f, aew=0.f;

  for (int i = e0; i < e1; ++i) {
    int s = csr_src[i];
    float4 k4 = ld4(&Kf[(size_t)s*HC + ch]);
    const __half2* ep = reinterpret_cast<const __half2*>(&EFh[(size_t)i*64 + 4*l16]);
    float2 e01 = __half22float2(ep[0]);
    float2 e23 = __half22float2(ep[1]);
    float p = q4.x*k4.x + q4.y*k4.y + q4.z*k4.z + q4.w*k4.w
            + w4.x*e01.x + w4.y*e01.y + w4.z*e23.x + w4.w*e23.y;
    p += __shfl_xor(p, 1);
    p += __shfl_xor(p, 2);
    p += __shfl_xor(p, 4);
    p += __shfl_xor(p, 8);
    float alpha = p * 0.125f;       // 1/sqrt(64)
    float mn = fmaxf(m, alpha);
    float sc = __expf(m - mn);      // -inf -> 0 on first edge
    float w  = __expf(alpha - mn);
    float4 v4 = ld4(&Vf[(size_t)s*HC + ch]);
    den = den*sc + w;
    avx = avx*sc + w*v4.x; avy = avy*sc + w*v4.y;
    avz = avz*sc + w*v4.z; avw = avw*sc + w*v4.w;
    aex = aex*sc + w*e01.x; aey = aey*sc + w*e01.y;
    aez = aez*sc + w*e23.x; aew = aew*sc + w*e23.y;
    m = mn;
  }
  float inv = den > 0.f ? 1.0f/den : 0.f;
  size_t oidx = (size_t)loc*HC + ch;
  float4 s4 = ld4(&Sc[oidx]);               // skip from lin_skip GEMM
  s4.x += avx*inv; s4.y += avy*inv; s4.z += avz*inv; s4.w += avw*inv;
  *reinterpret_cast<float4*>(&Sc[oidx]) = s4;
  float4 o2 = make_float4(aex*inv, aey*inv, aez*inv, aew*inv);
  *reinterpret_cast<float4*>(&SEc[oidx]) = o2;
}

// ---------------- mean pool (batch sorted) ----------------
__global__ void pool_kernel(const float* __restrict__ Hf, const int* __restrict__ batch,
                            float* __restrict__ gsum, int nNodes){
  const int CH = 64;
  int c = threadIdx.x & 63;
  int chunk = blockIdx.x * (blockDim.x >> 6) + (threadIdx.x >> 6);
  int n0 = chunk * CH;
  if (n0 >= nNodes) return;
  int n1 = min(n0 + CH, nNodes);
  float acc = 0.f;
  int g = batch[n0];
  for (int n = n0; n < n1; ++n) {
    int gn = batch[n];
    if (gn != g) { atomicAdd(&gsum[g*64 + c], acc); acc = 0.f; g = gn; }
    acc += Hf[(size_t)n*64 + c];
  }
  atomicAdd(&gsum[g*64 + c], acc);
}

// ---------------- MLP head ----------------
__global__ void mlp_kernel(const float* __restrict__ gsum, const int* __restrict__ batch,
                           int nNodes, int G,
                           const float* __restrict__ w1, const float* __restrict__ b1,
                           const float* __restrict__ w2, const float* __restrict__ b2,
                           const float* __restrict__ w3, const float* __restrict__ b3,
                           float* __restrict__ out){
  int g = threadIdx.x;
  if (g >= G) return;
  int lo = 0, hi = nNodes;
  while (lo < hi){ int mid = (lo+hi)>>1; if (batch[mid] < g) lo = mid+1; else hi = mid; }
  int first = lo;
  lo = 0; hi = nNodes;
  while (lo < hi){ int mid = (lo+hi)>>1; if (batch[mid] < g+1) lo = mid+1; else hi = mid; }
  int cnt = lo - first;
  float invc = 1.0f / fmaxf((float)cnt, 1.0f);
  float gm[64];
  #pragma unroll
  for (int c = 0; c < 64; ++c) gm[c] = gsum[g*64 + c] * invc;
  float r1[32];
  for (int j = 0; j < 32; ++j){
    float s = b1[j];
    for (int c = 0; c < 64; ++c) s = fmaf(gm[c], w1[c*32 + j], s);
    r1[j] = fmaxf(s, 0.f);
  }
  float r2[16];
  for (int j = 0; j < 16; ++j){
    float s = b2[j];
    for (int c = 0; c < 32; ++c) s = fmaf(r1[c], w2[c*16 + j], s);
    r2[j] = fmaxf(s, 0.f);
  }
  float s = b3[0];
  for (int c = 0; c < 16; ++c) s = fmaf(r2[c], w3[c], s);
  out[g] = s;
}

// ---------------------------------------------------------------------------
static inline void launch_gemm(hipStream_t st, const float* A, int lda, long aZ,
    const float* B, int ldb, long bZ, float* C, int ldc, long cZ,
    const float* bias, int M, int Ncols, int K, int Z, int mode,
    const float* ep1,
    const float* g, const float* b, const float* m, const float* v)
{
  dim3 grid((M + 127) / 128, Ncols / 64, Z);
  gemm_kernel<<<grid, 256, 0, st>>>(A, lda, aZ, B, ldb, bZ, C, ldc, cZ,
                                    bias, M, Ncols, K, mode, ep1, g, b, m, v);
}

struct ConvW {
  const float *wq,*bq,*wk,*bk,*wv,*bv,*we,*ws,*bs,*bg,*bb,*bm,*bv_;
};

static void run_conv(hipStream_t st, const float* Xin, int din, int H, const ConvW& W,
  int N, int C, float* OUT, float* Kf, float* Vf,
  float* Qc, float* QWEc, float* Sc, float* SEc,
  float* weT, const __half* EFh, const int* irow, const int* csr_s)
{
  const int hc = H * 64;
  // K, V: full-N (needed for gathers), read Xin before any overwrite
  launch_gemm(st, Xin, din, 0, W.wk, hc, 0, Kf, hc, 0, W.bk, N, hc, din, 1, 0, 0, 0,0,0,0);
  launch_gemm(st, Xin, din, 0, W.wv, hc, 0, Vf, hc, 0, W.bv, N, hc, din, 1, 0, 0, 0,0,0,0);
  transpose_we_kernel<<<(H*4096 + 255)/256, 256, 0, st>>>(W.we, weT, H, hc);

  for (int n0 = 0; n0 < N; n0 += C) {
    int Cc = min(C, N - n0);
    const float* Xc = Xin + (size_t)n0 * din;
    // per-chunk projections
    launch_gemm(st, Xc, din, 0, W.wq, hc, 0, Qc, hc, 0, W.bq, Cc, hc, din, 1, 0, 0, 0,0,0,0);
    launch_gemm(st, Xc, din, 0, W.ws, hc, 0, Sc, hc, 0, W.bs, Cc, hc, din, 1, 0, 0, 0,0,0,0);
    // qwe = Q @ weT (per head)
    launch_gemm(st, Qc, hc, 64, weT, 64, 4096, QWEc, hc, 64, nullptr, Cc, 64, 64, H, 0, 0, 0,0,0,0);
    // aggregation: Sc += att; SEc = sum(w*e)/den
    if (H == 4) {
      agg_kernel<256><<<(Cc + 3) / 4, 256, 0, st>>>(irow, csr_s, Qc, Kf, Vf, QWEc, EFh, Sc, SEc, n0, Cc);
    } else {
      agg_kernel<64><<<(Cc + 15) / 16, 256, 0, st>>>(irow, csr_s, Qc, Kf, Vf, QWEc, EFh, Sc, SEc, n0, Cc);
    }
    // out_chunk = (SE@we + Sc) -> BN -> ELU
    launch_gemm(st, SEc, hc, 64, W.we, hc, 64, OUT + (size_t)n0 * hc, hc, 64, nullptr,
                Cc, 64, 64, H, 2, Sc, W.bg, W.bb, W.bm, W.bv_);
  }
}

extern "C" void kernel_launch(void* const* d_in, const int* in_sizes, int n_in,
                              void* d_out, int out_size, void* d_ws, size_t ws_size,
                              hipStream_t stream) {
  (void)n_in;
  const float* x     = (const float*)d_in[0];
  const int*   ei    = (const int*)d_in[1];
  const float* eattr = (const float*)d_in[2];
  const int*   batch = (const int*)d_in[3];
  const float* ee_w1 = (const float*)d_in[4];
  const float* ee_b1 = (const float*)d_in[5];
  const float* ee_w2 = (const float*)d_in[6];
  const float* ee_b2 = (const float*)d_in[7];
  ConvW cw[3];
  {
    int t = 8;
    for (int c = 0; c < 3; ++c){
      cw[c].wq=(const float*)d_in[t++]; cw[c].bq=(const float*)d_in[t++];
      cw[c].wk=(const float*)d_in[t++]; cw[c].bk=(const float*)d_in[t++];
      cw[c].wv=(const float*)d_in[t++]; cw[c].bv=(const float*)d_in[t++];
      cw[c].we=(const float*)d_in[t++]; cw[c].ws=(const float*)d_in[t++]; cw[c].bs=(const float*)d_in[t++];
    }
    for (int c = 0; c < 3; ++c){
      cw[c].bg=(const float*)d_in[t++]; cw[c].bb=(const float*)d_in[t++];
      cw[c].bm=(const float*)d_in[t++]; cw[c].bv_=(const float*)d_in[t++];
    }
  }
  const float* r_w1 = (const float*)d_in[47];
  const float* r_b1 = (const float*)d_in[48];
  const float* r_w2 = (const float*)d_in[49];
  const float* r_b2 = (const float*)d_in[50];
  const float* r_w3 = (const float*)d_in[51];
  const float* r_b3 = (const float*)d_in[52];

  const int N = in_sizes[0] / 64;      // 50000
  const int E = in_sizes[2] / 16;      // 400000
  const int G = out_size;              // 128

  // ---- fixed workspace layout ----
  float* fws = (float*)d_ws;
  const size_t NB = (size_t)N * 256;           // floats per full slot
  float* slot_out = fws;                        // [N,256] conv output / next input
  float* slot_k   = slot_out + NB;              // [N,256] K
  float* slot_v   = slot_k + NB;                // [N,256] V
  __half* EFh     = (__half*)(slot_v + NB);     // [E,64] fp16, CSR order
  float* weT      = (float*)(EFh + (size_t)E*64);
  float* gsum     = weT + 16384;                // [G=128,64] -- zeroed
  int* ideg       = (int*)(gsum + 8192);        // N -- zeroed
  int* icnt       = ideg + N;                   // N -- zeroed
  int* irow       = icnt + N;                   // N+1
  int* csr_s      = irow + (N + 1);             // E
  int* csr_e      = csr_s + E;                  // E
  uintptr_t pcb   = ((uintptr_t)(csr_e + E) + 63) & ~(uintptr_t)63;
  uintptr_t wend  = (uintptr_t)d_ws + ws_size;

  // adaptive chunk size: 4 chunk slots of [C,256] fp32 -> 4096 B per node
  long availB = (long)wend - (long)pcb;
  long Cl = availB > 0 ? availB / 4096 : 0;
  if (Cl > N) Cl = N;
  int C = (int)(Cl & ~255L);
  if (C < 1024) {
    // cannot fit: leak ws_size (MB) + fixed (MB)/1000 through d_out
    size_t fixedB = (size_t)(pcb - (uintptr_t)d_ws);
    float val = (float)(ws_size >> 20) + (float)(fixedB >> 20) / 1000.0f;
    leak_kernel<<<(G + 255)/256, 256, 0, stream>>>((float*)d_out, G, val);
    return;
  }
  float* Qc   = (float*)pcb;
  float* QWEc = Qc   + (size_t)C * 256;
  float* Sc   = QWEc + (size_t)C * 256;
  float* SEc  = Sc   + (size_t)C * 256;

  // encoder scratch aliases (dead before convs):
  float* EFtmp = slot_out;                      // [E,64] fp32 over OUT..K (102.4 MB)
  float* hid   = slot_v;                        // [E,64] fp32 over V..EFh (102.4 MB)

  const int* src = ei;
  const int* dst = ei + E;

  // ---- zero accumulators (gsum, ideg, icnt contiguous) ----
  int zn = 8192 + 2 * N;
  zero_kernel<<<(zn + 255)/256, 256, 0, stream>>>((int*)gsum, zn);

  // ---- CSR by dst ----
  hist_kernel<<<(E + 255)/256, 256, 0, stream>>>(dst, ideg, E);
  scan_kernel<<<1, 1024, 0, stream>>>(ideg, irow, N);
  scatter_kernel<<<(E + 255)/256, 256, 0, stream>>>(src, dst, irow, icnt, csr_s, csr_e, E);

  // ---- edge encoder: e = relu(ea@W1+b1)@W2+b2, gather to CSR order as fp16 ----
  launch_gemm(stream, eattr, 16, 0, ee_w1, 64, 0, hid,   64, 0, ee_b1, E, 64, 16, 1, 1, 0, 0,0,0,0);
  launch_gemm(stream, hid,   64, 0, ee_w2, 64, 0, EFtmp, 64, 0, ee_b2, E, 64, 64, 1, 0, 0, 0,0,0,0);
  gather_ef_kernel<<<(E*16 + 255)/256, 256, 0, stream>>>(EFtmp, csr_e, EFh, E);

  // ---- conv 1: x[N,64] -> slot_out[N,256] ----
  run_conv(stream, x, 64, 4, cw[0], N, C, slot_out, slot_k, slot_v,
           Qc, QWEc, Sc, SEc, weT, EFh, irow, csr_s);
  // ---- conv 2: slot_out[N,256] -> slot_out[N,256] (per-chunk overwrite) ----
  run_conv(stream, slot_out, 256, 4, cw[1], N, C, slot_out, slot_k, slot_v,
           Qc, QWEc, Sc, SEc, weT, EFh, irow, csr_s);
  // ---- conv 3: slot_out[N,256] -> slot_out[N,64] (stride-64 over stride-256) ----
  run_conv(stream, slot_out, 256, 1, cw[2], N, C, slot_out, slot_k, slot_v,
           Qc, QWEc, Sc, SEc, weT, EFh, irow, csr_s);

  // ---- global mean pool + MLP ----
  {
    int chunks = (N + 63) / 64;
    int blocks = (chunks + 3) / 4;
    pool_kernel<<<blocks, 256, 0, stream>>>(slot_out, batch, gsum, N);
  }
  mlp_kernel<<<1, 128, 0, stream>>>(gsum, batch, N, G, r_w1, r_b1, r_w2, r_b2, r_w3, r_b3,
                                    (float*)d_out);
}

// Round 4
// 1068.397 us; speedup vs baseline: 1.9421x; 1.9421x over previous
//
#include <hip/hip_runtime.h>
#include <math.h>

// ---------------------------------------------------------------------------
// GTR_50139448214076: 3x TransformerConv GNN + BN/ELU + mean-pool + MLP
// All GEMMs on MFMA fp16 (split-weight hi + lo/2048 for fp32-grade weights),
// activations fp16 end-to-end, fp32 accumulation everywhere.
// Per conv: ONE fused projection GEMM X@[Wq|Wk|Wv|Wqe] -> PROJ[N,4*hc] (fp16),
// wave-per-node online-softmax aggregation (att,SE written into dead Q/QWE
// slices of PROJ), post GEMM [SE|X]@[blockdiag(we);ws] + att + BN + ELU.
// Identities: q.(k+e@we) = q.k + e.(q@we^T);  sum w*(v+e@we) = sum w*v + (sum w*e)@we
// Workspace ~210 MB.
// ---------------------------------------------------------------------------

typedef _Float16 f16;
typedef _Float16 half8  __attribute__((ext_vector_type(8)));
typedef _Float16 half4v __attribute__((ext_vector_type(4)));
typedef float    f32x4  __attribute__((ext_vector_type(4)));

__device__ __forceinline__ float4 ld4(const float* p){ return *reinterpret_cast<const float4*>(p); }

// ---------------- utility ----------------
__global__ void zero_kernel(int* __restrict__ p, int n){
  int i = blockIdx.x*blockDim.x + threadIdx.x;
  if (i < n) p[i] = 0;
}
__global__ void leak_kernel(float* __restrict__ out, int n, float val){
  int i = blockIdx.x*blockDim.x + threadIdx.x;
  if (i < n) out[i] = val;
}
__global__ void copyf_kernel(float* __restrict__ dst, const float* __restrict__ src, int n){
  int i = blockIdx.x*blockDim.x + threadIdx.x;
  if (i < n) dst[i] = src[i];
}
__global__ void cvt16_kernel(const float* __restrict__ src, f16* __restrict__ dst, int n){
  int i = blockIdx.x*blockDim.x + threadIdx.x;
  if (i < n) dst[i] = (f16)src[i];
}

// ---------------- CSR build ----------------
__global__ void hist_kernel(const int* __restrict__ dst, int* __restrict__ deg, int E){
  int i = blockIdx.x*blockDim.x + threadIdx.x;
  if (i < E) atomicAdd(&deg[dst[i]], 1);
}

__global__ __launch_bounds__(1024)
void scan_kernel(const int* __restrict__ deg, int* __restrict__ rowptr, int n){
  __shared__ int buf[1024];
  __shared__ int sbase;
  int tid = threadIdx.x;
  if (tid == 0){ sbase = 0; rowptr[0] = 0; }
  __syncthreads();
  for (int start = 0; start < n; start += 4096){
    int i0 = start + tid*4;
    int a0 = (i0+0<n)?deg[i0+0]:0;
    int a1 = (i0+1<n)?deg[i0+1]:0;
    int a2 = (i0+2<n)?deg[i0+2]:0;
    int a3 = (i0+3<n)?deg[i0+3]:0;
    int s = a0+a1+a2+a3;
    int v = s;
    buf[tid] = v;
    __syncthreads();
    for (int off=1; off<1024; off<<=1){
      int t = (tid >= off) ? buf[tid-off] : 0;
      __syncthreads();
      v += t;
      buf[tid] = v;
      __syncthreads();
    }
    int pre = sbase + v - s;
    if (i0+0 < n) rowptr[i0+1] = pre + a0;
    if (i0+1 < n) rowptr[i0+2] = pre + a0 + a1;
    if (i0+2 < n) rowptr[i0+3] = pre + a0 + a1 + a2;
    if (i0+3 < n) rowptr[i0+4] = pre + s;
    __syncthreads();
    if (tid == 1023) sbase += buf[1023];
    __syncthreads();
  }
}

__global__ void scatter_kernel(const int* __restrict__ src, const int* __restrict__ dst,
                               const int* __restrict__ rowptr, int* __restrict__ cnt,
                               int* __restrict__ csr_src, int* __restrict__ csr_eid, int E){
  int i = blockIdx.x*blockDim.x + threadIdx.x;
  if (i >= E) return;
  int d = dst[i];
  int pos = rowptr[d] + atomicAdd(&cnt[d], 1);
  csr_src[pos] = src[i];
  csr_eid[pos] = i;
}

// EFh[i] = EFt[csr_eid[i]]  (fp16 edge features -> CSR order)
__global__ void gather_ef16_kernel(const f16* __restrict__ EFt, const int* __restrict__ csr_eid,
                                   f16* __restrict__ EFh, int E){
  int i = blockIdx.x*blockDim.x + threadIdx.x;   // E*8 chunks of 8 halves
  if (i >= E*8) return;
  int e = i >> 3, j8 = (i & 7) * 8;
  *(half8*)(EFh + (size_t)e*64 + j8) = *(const half8*)(EFt + (size_t)csr_eid[e]*64 + j8);
}

// ---------------- weight prep ----------------
// Wqe[d, h*64+j] = sum_c wq[d,h*64+c]*we[j,h*64+c];  bqe likewise from bq.
__global__ void wqe_kernel(const float* __restrict__ wq, const float* __restrict__ bq,
                           const float* __restrict__ we, float* __restrict__ Wqe,
                           float* __restrict__ bqe, int din, int H){
  int hc = H*64;
  int i = blockIdx.x*blockDim.x + threadIdx.x;
  if (i >= (din+1)*hc) return;
  int d = i / hc, col = i - d*hc;
  int h = col >> 6, j = col & 63;
  const float* qsub = ((d < din) ? (wq + (size_t)d*hc) : bq) + h*64;
  const float* wrow = we + (size_t)j*hc + h*64;
  float s = 0.f;
  #pragma unroll 8
  for (int c = 0; c < 64; ++c) s += qsub[c] * wrow[c];
  if (d < din) Wqe[(size_t)d*hc + col] = s;
  else bqe[col] = s;
}

// pack fp32 src[K, Csub] (row stride lds) into B^T hi/lo [coloff+c][Kp], zero-pad k>=K
__global__ void packB_kernel(const float* __restrict__ src, int lds, int K, int Csub, int coloff,
                             f16* __restrict__ Bhi, f16* __restrict__ Blo, int Kp){
  int i = blockIdx.x*blockDim.x + threadIdx.x;
  if (i >= Csub*Kp) return;
  int c = i / Kp, k = i - c*Kp;
  float v = (k < K) ? src[(size_t)k*lds + c] : 0.f;
  f16 hi = (f16)v;
  f16 lo = (f16)((v - (float)hi) * 2048.0f);
  Bhi[(size_t)(coloff+c)*Kp + k] = hi;
  Blo[(size_t)(coloff+c)*Kp + k] = lo;
}

// B^T pack for post GEMM: k<hc -> blockdiag(we) (head-matched), k in [hc,hc+din) -> ws
__global__ void packBpost_kernel(const float* __restrict__ we, const float* __restrict__ ws,
                                 int din, int hc,
                                 f16* __restrict__ Bhi, f16* __restrict__ Blo, int Kp){
  int i = blockIdx.x*blockDim.x + threadIdx.x;
  if (i >= hc*Kp) return;
  int c = i / Kp, k = i - c*Kp;
  float v = 0.f;
  if (k < hc) { if ((k>>6) == (c>>6)) v = we[(size_t)(k&63)*hc + c]; }
  else if (k < hc + din) v = ws[(size_t)(k-hc)*hc + c];
  f16 hi = (f16)v;
  f16 lo = (f16)((v - (float)hi) * 2048.0f);
  Bhi[(size_t)c*Kp + k] = hi;
  Blo[(size_t)c*Kp + k] = lo;
}

// ---------------- MFMA fp16 GEMM (split-weight) ----------------
// C[M, Ncols] = [A1 | A2] @ (Bhi + Blo/2048) + bias, optional epilogues.
// A: fp16, k<K1 from A1, K1<=k<K1+K2 from A2, zero beyond. B^T packed [col][Kp].
// mode 0: +bias; 1: +bias,relu; 2: +bias +ep(f16) +BN +ELU. Output fp16.
__device__ __forceinline__ float bn_elu(float x, float g, float b, float m, float v){
  float s = g / sqrtf(v + 1e-5f);
  float y = (x - m) * s + b;
  return y > 0.f ? y : expm1f(y);
}

__global__ __launch_bounds__(256)
void hgemm_kernel(const f16* __restrict__ A1, int lda1, int K1,
                  const f16* __restrict__ A2, int lda2, int K2,
                  const f16* __restrict__ Bhi, const f16* __restrict__ Blo, int Kp,
                  const float* __restrict__ bias,
                  f16* __restrict__ C, int ldc, int M, int mode,
                  const f16* __restrict__ ep, int ldep,
                  const float* __restrict__ bng, const float* __restrict__ bnb,
                  const float* __restrict__ bnm, const float* __restrict__ bnv)
{
  __shared__ f16 As[128*40];
  __shared__ f16 Bh[64*40];
  __shared__ f16 Bl[64*40];
  const int tid  = threadIdx.x;
  const int lane = tid & 63;
  const int wave = tid >> 6;
  const int wm = wave >> 1, wn = wave & 1;         // 2x2 wave grid, 64x32 each
  const int row0 = blockIdx.x * 128;
  const int col0 = blockIdx.y * 64;
  const int l15 = lane & 15;
  const int lk  = (lane >> 4) * 8;
  const int Kend = K1 + K2;

  f32x4 acch[8], accl[8];
  #pragma unroll
  for (int i=0;i<8;i++){
    acch[i][0]=0.f; acch[i][1]=0.f; acch[i][2]=0.f; acch[i][3]=0.f;
    accl[i][0]=0.f; accl[i][1]=0.f; accl[i][2]=0.f; accl[i][3]=0.f;
  }

  for (int k0 = 0; k0 < Kp; k0 += 32) {
    #pragma unroll
    for (int t=0;t<2;t++){
      int idx = t*256 + tid;
      int r = idx >> 2, kc = (idx & 3) * 8;
      int kg = k0 + kc;
      int grow = row0 + r;
      half8 v;
      #pragma unroll
      for (int q=0;q<8;q++) v[q] = (f16)0.f;
      if (grow < M){
        if (kg < K1)       v = *(const half8*)(A1 + (size_t)grow*lda1 + kg);
        else if (kg < Kend) v = *(const half8*)(A2 + (size_t)grow*lda2 + (kg - K1));
      }
      *(half8*)(As + r*40 + kc) = v;
    }
    {
      int r = tid >> 2, kc = (tid & 3) * 8;
      int kg = k0 + kc;
      *(half8*)(Bh + r*40 + kc) = *(const half8*)(Bhi + (size_t)(col0 + r)*Kp + kg);
      *(half8*)(Bl + r*40 + kc) = *(const half8*)(Blo + (size_t)(col0 + r)*Kp + kg);
    }
    __syncthreads();
    half8 af[4], bfh[2], bfl[2];
    #pragma unroll
    for (int mf=0; mf<4; mf++) af[mf] = *(const half8*)(As + (wm*64 + mf*16 + l15)*40 + lk);
    #pragma unroll
    for (int nf=0; nf<2; nf++){
      bfh[nf] = *(const half8*)(Bh + (wn*32 + nf*16 + l15)*40 + lk);
      bfl[nf] = *(const half8*)(Bl + (wn*32 + nf*16 + l15)*40 + lk);
    }
    #pragma unroll
    for (int mf=0; mf<4; mf++)
      #pragma unroll
      for (int nf=0; nf<2; nf++){
        acch[mf*2+nf] = __builtin_amdgcn_mfma_f32_16x16x32_f16(af[mf], bfh[nf], acch[mf*2+nf], 0,0,0);
        accl[mf*2+nf] = __builtin_amdgcn_mfma_f32_16x16x32_f16(af[mf], bfl[nf], accl[mf*2+nf], 0,0,0);
      }
    __syncthreads();
  }

  // epilogue: C/D layout col=lane&15, row=(lane>>4)*4+reg
  #pragma unroll
  for (int mf=0; mf<4; mf++)
    #pragma unroll
    for (int nf=0; nf<2; nf++){
      int col  = col0 + wn*32 + nf*16 + l15;
      int rowb = row0 + wm*64 + mf*16 + (lane>>4)*4;
      float bi = bias ? bias[col] : 0.f;
      #pragma unroll
      for (int i=0;i<4;i++){
        int row = rowb + i;
        if (row >= M) continue;
        float r = acch[mf*2+nf][i] + accl[mf*2+nf][i] * (1.0f/2048.0f) + bi;
        if (mode == 1) r = fmaxf(r, 0.f);
        else if (mode == 2){
          r += (float)ep[(size_t)row*ldep + col];
          r = bn_elu(r, bng[col], bnb[col], bnm[col], bnv[col]);
        }
        C[(size_t)row*ldc + col] = (f16)r;
      }
    }
}

// ---------------- aggregation: online softmax over in-edges (fp16 I/O) ------
// PROJ row layout (stride ldp = 4*HC): [Q | K | V | QWE] each HC wide.
// att overwrites Q slice, SE overwrites QWE slice (own row only).
template<int HC>
__global__ __launch_bounds__(256)
void agg16_kernel(const int* __restrict__ rowptr, const int* __restrict__ csr_src,
                  f16* __restrict__ PROJ, int ldp, const f16* __restrict__ EFh, int nNodes)
{
  int lane = threadIdx.x & 63;
  int wid = (blockIdx.x * blockDim.x + threadIdx.x) >> 6;
  int grp = lane >> 4, l16 = lane & 15;
  int node, ch;
  if (HC == 256) { node = wid;          ch = 4*lane; }
  else           { node = wid*4 + grp;  ch = 4*l16;  }
  if (node >= nNodes) return;
  f16* rowp = PROJ + (size_t)node*ldp;
  half4v qh = *(const half4v*)(rowp + ch);
  half4v wh = *(const half4v*)(rowp + 3*HC + ch);
  float q0=qh[0],q1=qh[1],q2=qh[2],q3=qh[3];
  float w0=wh[0],w1=wh[1],w2=wh[2],w3=wh[3];
  int e0 = rowptr[node], e1 = rowptr[node+1];

  float m = -INFINITY, den = 0.f;
  float avx=0.f,avy=0.f,avz=0.f,avw=0.f, aex=0.f,aey=0.f,aez=0.f,aew=0.f;

  for (int i = e0; i < e1; ++i) {
    int s = csr_src[i];
    const f16* srow = PROJ + (size_t)s*ldp;
    half4v k4 = *(const half4v*)(srow + HC + ch);
    half4v e4 = *(const half4v*)(EFh + (size_t)i*64 + 4*l16);
    float ex=e4[0], ey=e4[1], ez=e4[2], ew=e4[3];
    float p = q0*(float)k4[0] + q1*(float)k4[1] + q2*(float)k4[2] + q3*(float)k4[3]
            + w0*ex + w1*ey + w2*ez + w3*ew;
    p += __shfl_xor(p, 1);
    p += __shfl_xor(p, 2);
    p += __shfl_xor(p, 4);
    p += __shfl_xor(p, 8);
    float alpha = p * 0.125f;       // 1/sqrt(64)
    float mn = fmaxf(m, alpha);
    float sc = __expf(m - mn);      // -inf -> 0 on first edge
    float w  = __expf(alpha - mn);
    half4v v4 = *(const half4v*)(srow + 2*HC + ch);
    den = den*sc + w;
    avx = avx*sc + w*(float)v4[0]; avy = avy*sc + w*(float)v4[1];
    avz = avz*sc + w*(float)v4[2]; avw = avw*sc + w*(float)v4[3];
    aex = aex*sc + w*ex; aey = aey*sc + w*ey;
    aez = aez*sc + w*ez; aew = aew*sc + w*ew;
    m = mn;
  }
  float inv = den > 0.f ? 1.0f/den : 0.f;
  half4v o1, o2;
  o1[0]=(f16)(avx*inv); o1[1]=(f16)(avy*inv); o1[2]=(f16)(avz*inv); o1[3]=(f16)(avw*inv);
  o2[0]=(f16)(aex*inv); o2[1]=(f16)(aey*inv); o2[2]=(f16)(aez*inv); o2[3]=(f16)(aew*inv);
  *(half4v*)(rowp + ch) = o1;
  *(half4v*)(rowp + 3*HC + ch) = o2;
}

// ---------------- mean pool (batch sorted, fp16 in) ----------------
__global__ void pool16_kernel(const f16* __restrict__ Hf, const int* __restrict__ batch,
                              float* __restrict__ gsum, int nNodes){
  const int CH = 64;
  int c = threadIdx.x & 63;
  int chunk = blockIdx.x * (blockDim.x >> 6) + (threadIdx.x >> 6);
  int n0 = chunk * CH;
  if (n0 >= nNodes) return;
  int n1 = min(n0 + CH, nNodes);
  float acc = 0.f;
  int g = batch[n0];
  for (int n = n0; n < n1; ++n) {
    int gn = batch[n];
    if (gn != g) { atomicAdd(&gsum[g*64 + c], acc); acc = 0.f; g = gn; }
    acc += (float)Hf[(size_t)n*64 + c];
  }
  atomicAdd(&gsum[g*64 + c], acc);
}

// ---------------- MLP head (fp32) ----------------
__global__ void mlp_kernel(const float* __restrict__ gsum, const int* __restrict__ batch,
                           int nNodes, int G,
                           const float* __restrict__ w1, const float* __restrict__ b1,
                           const float* __restrict__ w2, const float* __restrict__ b2,
                           const float* __restrict__ w3, const float* __restrict__ b3,
                           float* __restrict__ out){
  int g = threadIdx.x;
  if (g >= G) return;
  int lo = 0, hi = nNodes;
  while (lo < hi){ int mid = (lo+hi)>>1; if (batch[mid] < g) lo = mid+1; else hi = mid; }
  int first = lo;
  lo = 0; hi = nNodes;
  while (lo < hi){ int mid = (lo+hi)>>1; if (batch[mid] < g+1) lo = mid+1; else hi = mid; }
  int cnt = lo - first;
  float invc = 1.0f / fmaxf((float)cnt, 1.0f);
  float gm[64];
  #pragma unroll
  for (int c = 0; c < 64; ++c) gm[c] = gsum[g*64 + c] * invc;
  float r1[32];
  for (int j = 0; j < 32; ++j){
    float s = b1[j];
    for (int c = 0; c < 64; ++c) s = fmaf(gm[c], w1[c*32 + j], s);
    r1[j] = fmaxf(s, 0.f);
  }
  float r2[16];
  for (int j = 0; j < 16; ++j){
    float s = b2[j];
    for (int c = 0; c < 32; ++c) s = fmaf(r1[c], w2[c*16 + j], s);
    r2[j] = fmaxf(s, 0.f);
  }
  float s = b3[0];
  for (int c = 0; c < 16; ++c) s = fmaf(r2[c], w3[c], s);
  out[g] = s;
}

// ---------------------------------------------------------------------------
static inline void launch_hgemm(hipStream_t st,
    const f16* A1, int lda1, int K1, const f16* A2, int lda2, int K2,
    const f16* Bhi, const f16* Blo, int Kp, const float* bias,
    f16* C, int ldc, int M, int Ncols, int mode,
    const f16* ep, int ldep,
    const float* g, const float* b, const float* m, const float* v)
{
  dim3 grid((M + 127) / 128, Ncols / 64, 1);
  hgemm_kernel<<<grid, 256, 0, st>>>(A1, lda1, K1, A2, lda2, K2, Bhi, Blo, Kp,
                                     bias, C, ldc, M, mode, ep, ldep, g, b, m, v);
}

struct ConvW {
  const float *wq,*bq,*wk,*bk,*wv,*bv,*we,*ws,*bs,*bg,*bb,*bm,*bv_;
};

extern "C" void kernel_launch(void* const* d_in, const int* in_sizes, int n_in,
                              void* d_out, int out_size, void* d_ws, size_t ws_size,
                              hipStream_t stream) {
  (void)n_in;
  const float* x     = (const float*)d_in[0];
  const int*   ei    = (const int*)d_in[1];
  const float* eattr = (const float*)d_in[2];
  const int*   batch = (const int*)d_in[3];
  const float* ee_w1 = (const float*)d_in[4];
  const float* ee_b1 = (const float*)d_in[5];
  const float* ee_w2 = (const float*)d_in[6];
  const float* ee_b2 = (const float*)d_in[7];
  ConvW cw[3];
  {
    int t = 8;
    for (int c = 0; c < 3; ++c){
      cw[c].wq=(const float*)d_in[t++]; cw[c].bq=(const float*)d_in[t++];
      cw[c].wk=(const float*)d_in[t++]; cw[c].bk=(const float*)d_in[t++];
      cw[c].wv=(const float*)d_in[t++]; cw[c].bv=(const float*)d_in[t++];
      cw[c].we=(const float*)d_in[t++]; cw[c].ws=(const float*)d_in[t++]; cw[c].bs=(const float*)d_in[t++];
    }
    for (int c = 0; c < 3; ++c){
      cw[c].bg=(const float*)d_in[t++]; cw[c].bb=(const float*)d_in[t++];
      cw[c].bm=(const float*)d_in[t++]; cw[c].bv_=(const float*)d_in[t++];
    }
  }
  const float* r_w1 = (const float*)d_in[47];
  const float* r_b1 = (const float*)d_in[48];
  const float* r_w2 = (const float*)d_in[49];
  const float* r_b2 = (const float*)d_in[50];
  const float* r_w3 = (const float*)d_in[51];
  const float* r_b3 = (const float*)d_in[52];

  const int N = in_sizes[0] / 64;      // 50000
  const int E = in_sizes[2] / 16;      // 400000
  const int G = out_size;              // 128

  // ---- workspace layout ----
  char* wp = (char*)d_ws;
  f16* HA   = (f16*)wp;            wp += (size_t)N*256*2;   // 25.6 MB
  f16* HB   = (f16*)wp;            wp += (size_t)N*256*2;   // 25.6 MB
  f16* PROJ = (f16*)wp;            wp += (size_t)N*1024*2;  // 102.4 MB
  f16* EFh  = (f16*)wp;            wp += (size_t)E*64*2;    // 51.2 MB
  f16* Bhi  = (f16*)wp;            wp += 262144*2;          // 512 KB
  f16* Blo  = (f16*)wp;            wp += 262144*2;          // 512 KB
  float* WqeS  = (float*)wp;       wp += 65536*4;           // 256 KB
  float* biasP = (float*)wp;       wp += 1024*4;
  float* gsum  = (float*)wp;       wp += 8192*4;
  int* ideg  = (int*)wp;           wp += (size_t)N*4;
  int* icnt  = (int*)wp;           wp += (size_t)N*4;
  int* irow  = (int*)wp;           wp += (size_t)(N+1)*4;
  int* csr_s = (int*)wp;           wp += (size_t)E*4;
  int* csr_e = (int*)wp;           wp += (size_t)E*4;
  size_t used = (size_t)(wp - (char*)d_ws);
  if (used > ws_size) {
    leak_kernel<<<(G + 255)/256, 256, 0, stream>>>((float*)d_out, G, (float)(ws_size >> 20));
    return;
  }
  // encoder-phase aliases (dead before convs):
  f16* EA16  = HA;                 // [E,16]  6.4M halves <= 12.8M
  f16* HID   = PROJ;               // [E,64]  25.6M halves
  f16* EFtmp = PROJ + (size_t)E*64;// [E,64]  25.6M halves (PROJ total 51.2M)

  const int* src = ei;
  const int* dst = ei + E;

  // ---- zero gsum/deg/cnt (contiguous) ----
  zero_kernel<<<(8192 + 2*N + 255)/256, 256, 0, stream>>>((int*)gsum, 8192 + 2*N);

  // ---- CSR by dst ----
  hist_kernel<<<(E + 255)/256, 256, 0, stream>>>(dst, ideg, E);
  scan_kernel<<<1, 1024, 0, stream>>>(ideg, irow, N);
  scatter_kernel<<<(E + 255)/256, 256, 0, stream>>>(src, dst, irow, icnt, csr_s, csr_e, E);

  // ---- edge encoder (fp16 MFMA): e = relu(ea@W1+b1)@W2+b2 ----
  cvt16_kernel<<<(E*16 + 255)/256, 256, 0, stream>>>(eattr, EA16, E*16);
  packB_kernel<<<(64*32 + 255)/256, 256, 0, stream>>>(ee_w1, 64, 16, 64, 0, Bhi, Blo, 32);
  launch_hgemm(stream, EA16, 16, 16, nullptr, 0, 0, Bhi, Blo, 32, ee_b1,
               HID, 64, E, 64, 1, nullptr, 0, 0,0,0,0);
  packB_kernel<<<(64*64 + 255)/256, 256, 0, stream>>>(ee_w2, 64, 64, 64, 0, Bhi, Blo, 64);
  launch_hgemm(stream, HID, 64, 64, nullptr, 0, 0, Bhi, Blo, 64, ee_b2,
               EFtmp, 64, E, 64, 0, nullptr, 0, 0,0,0,0);
  gather_ef16_kernel<<<(E*8 + 255)/256, 256, 0, stream>>>(EFtmp, csr_e, EFh, E);

  // ---- x -> fp16 (EA16 dead now) ----
  cvt16_kernel<<<(N*64 + 255)/256, 256, 0, stream>>>(x, HA, N*64);

  // ================= conv layers =================
  // conv c: din, H, input Xin(ld dx), output Hout(ld hc)
  for (int c = 0; c < 3; ++c) {
    const int din = (c == 0) ? 64 : 256;
    const int H   = (c == 2) ? 1 : 4;
    const int hc  = H * 64;
    const int ldp = 4 * hc;
    const f16* Xin = (c == 0) ? HA : ((c == 1) ? HB : HA);
    const int  ldx = (c == 0) ? 64 : 256;
    f16* Hout = (c == 1) ? HA : HB;
    const ConvW& W = cw[c];

    // combined qwe weights + packed proj B = [Wq|Wk|Wv|Wqe], bias = [bq|bk|bv|bqe]
    wqe_kernel<<<((din+1)*hc + 255)/256, 256, 0, stream>>>(W.wq, W.bq, W.we, WqeS, biasP + 3*hc, din, H);
    int Kp = din;  // din is 64 or 256, both mult of 32
    packB_kernel<<<(hc*Kp + 255)/256, 256, 0, stream>>>(W.wq, hc, din, hc, 0,    Bhi, Blo, Kp);
    packB_kernel<<<(hc*Kp + 255)/256, 256, 0, stream>>>(W.wk, hc, din, hc, hc,   Bhi, Blo, Kp);
    packB_kernel<<<(hc*Kp + 255)/256, 256, 0, stream>>>(W.wv, hc, din, hc, 2*hc, Bhi, Blo, Kp);
    packB_kernel<<<(hc*Kp + 255)/256, 256, 0, stream>>>(WqeS, hc, din, hc, 3*hc, Bhi, Blo, Kp);
    copyf_kernel<<<(hc + 255)/256, 256, 0, stream>>>(biasP,        W.bq, hc);
    copyf_kernel<<<(hc + 255)/256, 256, 0, stream>>>(biasP + hc,   W.bk, hc);
    copyf_kernel<<<(hc + 255)/256, 256, 0, stream>>>(biasP + 2*hc, W.bv, hc);

    // fused projection: PROJ = Xin @ [Wq|Wk|Wv|Wqe] + biasP   [N, 4*hc] fp16
    launch_hgemm(stream, Xin, ldx, din, nullptr, 0, 0, Bhi, Blo, Kp, biasP,
                 PROJ, ldp, N, 4*hc, 0, nullptr, 0, 0,0,0,0);

    // aggregation (att -> Q slice, SE -> QWE slice)
    if (H == 4) agg16_kernel<256><<<(N + 3)/4,  256, 0, stream>>>(irow, csr_s, PROJ, ldp, EFh, N);
    else        agg16_kernel<64> <<<(N + 15)/16,256, 0, stream>>>(irow, csr_s, PROJ, ldp, EFh, N);

    // post: Hout = BN_ELU( [SE | Xin] @ [blockdiag(we); ws] + bs + att )
    int Kpp = hc + din;  // 320, 512, 320 -- all mult of 32
    packBpost_kernel<<<(hc*Kpp + 255)/256, 256, 0, stream>>>(W.we, W.ws, din, hc, Bhi, Blo, Kpp);
    launch_hgemm(stream, PROJ + 3*hc, ldp, hc, Xin, ldx, din, Bhi, Blo, Kpp, W.bs,
                 Hout, hc, N, hc, 2, PROJ, ldp, W.bg, W.bb, W.bm, W.bv_);
  }

  // ---- global mean pool + MLP ----
  {
    int chunks = (N + 63) / 64;
    pool16_kernel<<<(chunks + 3)/4, 256, 0, stream>>>(HB, batch, gsum, N);
  }
  mlp_kernel<<<1, 128, 0, stream>>>(gsum, batch, N, G, r_w1, r_b1, r_w2, r_b2, r_w3, r_b3,
                                    (float*)d_out);
}

// Round 5
// 1055.308 us; speedup vs baseline: 1.9661x; 1.0124x over previous
//
#include <hip/hip_runtime.h>
#include <math.h>

// ---------------------------------------------------------------------------
// GTR_50139448214076: 3x TransformerConv GNN + BN/ELU + mean-pool + MLP
// All GEMMs on MFMA fp16 (split-weight hi + lo/2048), activations fp16,
// fp32 accumulation. Per conv: ONE fused projection GEMM X@[Wq|Wk|Wv|Wqe],
// wave-per-node online-softmax aggregation, post GEMM [SE|X]@[bd(we);ws].
// R5: XCD-chunked bijective block swizzle (col-fastest) for A-tile L2 reuse;
//     plane-separated LDS (bank-conflict-free ds_read_b128).
// ---------------------------------------------------------------------------

typedef _Float16 f16;
typedef _Float16 half8  __attribute__((ext_vector_type(8)));
typedef _Float16 half4v __attribute__((ext_vector_type(4)));
typedef float    f32x4  __attribute__((ext_vector_type(4)));

__device__ __forceinline__ float4 ld4(const float* p){ return *reinterpret_cast<const float4*>(p); }

// ---------------- utility ----------------
__global__ void zero_kernel(int* __restrict__ p, int n){
  int i = blockIdx.x*blockDim.x + threadIdx.x;
  if (i < n) p[i] = 0;
}
__global__ void leak_kernel(float* __restrict__ out, int n, float val){
  int i = blockIdx.x*blockDim.x + threadIdx.x;
  if (i < n) out[i] = val;
}
__global__ void copyf_kernel(float* __restrict__ dst, const float* __restrict__ src, int n){
  int i = blockIdx.x*blockDim.x + threadIdx.x;
  if (i < n) dst[i] = src[i];
}
__global__ void cvt16_kernel(const float* __restrict__ src, f16* __restrict__ dst, int n){
  int i = blockIdx.x*blockDim.x + threadIdx.x;
  if (i < n) dst[i] = (f16)src[i];
}

// ---------------- CSR build ----------------
__global__ void hist_kernel(const int* __restrict__ dst, int* __restrict__ deg, int E){
  int i = blockIdx.x*blockDim.x + threadIdx.x;
  if (i < E) atomicAdd(&deg[dst[i]], 1);
}

__global__ __launch_bounds__(1024)
void scan_kernel(const int* __restrict__ deg, int* __restrict__ rowptr, int n){
  __shared__ int buf[1024];
  __shared__ int sbase;
  int tid = threadIdx.x;
  if (tid == 0){ sbase = 0; rowptr[0] = 0; }
  __syncthreads();
  for (int start = 0; start < n; start += 4096){
    int i0 = start + tid*4;
    int a0 = (i0+0<n)?deg[i0+0]:0;
    int a1 = (i0+1<n)?deg[i0+1]:0;
    int a2 = (i0+2<n)?deg[i0+2]:0;
    int a3 = (i0+3<n)?deg[i0+3]:0;
    int s = a0+a1+a2+a3;
    int v = s;
    buf[tid] = v;
    __syncthreads();
    for (int off=1; off<1024; off<<=1){
      int t = (tid >= off) ? buf[tid-off] : 0;
      __syncthreads();
      v += t;
      buf[tid] = v;
      __syncthreads();
    }
    int pre = sbase + v - s;
    if (i0+0 < n) rowptr[i0+1] = pre + a0;
    if (i0+1 < n) rowptr[i0+2] = pre + a0 + a1;
    if (i0+2 < n) rowptr[i0+3] = pre + a0 + a1 + a2;
    if (i0+3 < n) rowptr[i0+4] = pre + s;
    __syncthreads();
    if (tid == 1023) sbase += buf[1023];
    __syncthreads();
  }
}

__global__ void scatter_kernel(const int* __restrict__ src, const int* __restrict__ dst,
                               const int* __restrict__ rowptr, int* __restrict__ cnt,
                               int* __restrict__ csr_src, int* __restrict__ csr_eid, int E){
  int i = blockIdx.x*blockDim.x + threadIdx.x;
  if (i >= E) return;
  int d = dst[i];
  int pos = rowptr[d] + atomicAdd(&cnt[d], 1);
  csr_src[pos] = src[i];
  csr_eid[pos] = i;
}

// EFh[i] = EFt[csr_eid[i]]  (fp16 edge features -> CSR order)
__global__ void gather_ef16_kernel(const f16* __restrict__ EFt, const int* __restrict__ csr_eid,
                                   f16* __restrict__ EFh, int E){
  int i = blockIdx.x*blockDim.x + threadIdx.x;   // E*8 chunks of 8 halves
  if (i >= E*8) return;
  int e = i >> 3, j8 = (i & 7) * 8;
  *(half8*)(EFh + (size_t)e*64 + j8) = *(const half8*)(EFt + (size_t)csr_eid[e]*64 + j8);
}

// ---------------- weight prep ----------------
// Wqe[d, h*64+j] = sum_c wq[d,h*64+c]*we[j,h*64+c];  bqe likewise from bq.
__global__ void wqe_kernel(const float* __restrict__ wq, const float* __restrict__ bq,
                           const float* __restrict__ we, float* __restrict__ Wqe,
                           float* __restrict__ bqe, int din, int H){
  int hc = H*64;
  int i = blockIdx.x*blockDim.x + threadIdx.x;
  if (i >= (din+1)*hc) return;
  int d = i / hc, col = i - d*hc;
  int h = col >> 6, j = col & 63;
  const float* qsub = ((d < din) ? (wq + (size_t)d*hc) : bq) + h*64;
  const float* wrow = we + (size_t)j*hc + h*64;
  float s = 0.f;
  #pragma unroll 8
  for (int c = 0; c < 64; ++c) s += qsub[c] * wrow[c];
  if (d < din) Wqe[(size_t)d*hc + col] = s;
  else bqe[col] = s;
}

// pack fp32 src[K, Csub] (row stride lds) into B^T hi/lo [coloff+c][Kp], zero-pad k>=K
__global__ void packB_kernel(const float* __restrict__ src, int lds, int K, int Csub, int coloff,
                             f16* __restrict__ Bhi, f16* __restrict__ Blo, int Kp){
  int i = blockIdx.x*blockDim.x + threadIdx.x;
  if (i >= Csub*Kp) return;
  int c = i / Kp, k = i - c*Kp;
  float v = (k < K) ? src[(size_t)k*lds + c] : 0.f;
  f16 hi = (f16)v;
  f16 lo = (f16)((v - (float)hi) * 2048.0f);
  Bhi[(size_t)(coloff+c)*Kp + k] = hi;
  Blo[(size_t)(coloff+c)*Kp + k] = lo;
}

// B^T pack for post GEMM: k<hc -> blockdiag(we) (head-matched), k in [hc,hc+din) -> ws
__global__ void packBpost_kernel(const float* __restrict__ we, const float* __restrict__ ws,
                                 int din, int hc,
                                 f16* __restrict__ Bhi, f16* __restrict__ Blo, int Kp){
  int i = blockIdx.x*blockDim.x + threadIdx.x;
  if (i >= hc*Kp) return;
  int c = i / Kp, k = i - c*Kp;
  float v = 0.f;
  if (k < hc) { if ((k>>6) == (c>>6)) v = we[(size_t)(k&63)*hc + c]; }
  else if (k < hc + din) v = ws[(size_t)(k-hc)*hc + c];
  f16 hi = (f16)v;
  f16 lo = (f16)((v - (float)hi) * 2048.0f);
  Bhi[(size_t)c*Kp + k] = hi;
  Blo[(size_t)c*Kp + k] = lo;
}

// ---------------- MFMA fp16 GEMM (split-weight) ----------------
// C[M, Ncols] = [A1 | A2] @ (Bhi + Blo/2048) + bias, optional epilogues.
// Grid: (Ncols/64, ceil(M/128)). XCD-chunked bijective swizzle, col fastest.
// mode 0: +bias; 1: +bias,relu; 2: +bias +ep(f16) +BN +ELU. Output fp16.
__device__ __forceinline__ float bn_elu(float x, float g, float b, float m, float v){
  float s = g / sqrtf(v + 1e-5f);
  float y = (x - m) * s + b;
  return y > 0.f ? y : expm1f(y);
}

__global__ __launch_bounds__(256)
void hgemm_kernel(const f16* __restrict__ A1, int lda1, int K1,
                  const f16* __restrict__ A2, int lda2, int K2,
                  const f16* __restrict__ Bhi, const f16* __restrict__ Blo, int Kp,
                  const float* __restrict__ bias,
                  f16* __restrict__ C, int ldc, int M, int mode,
                  const f16* __restrict__ ep, int ldep,
                  const float* __restrict__ bng, const float* __restrict__ bnb,
                  const float* __restrict__ bnm, const float* __restrict__ bnv)
{
  // plane-separated LDS: bank = (4*row)%32, uniform 2-way (free) on b128 ops
  __shared__ f16 As[4][128][8];
  __shared__ f16 Bh[4][64][8];
  __shared__ f16 Bl[4][64][8];
  const int tid  = threadIdx.x;
  const int lane = tid & 63;
  const int wave = tid >> 6;
  const int wm = wave >> 1, wn = wave & 1;         // 2x2 wave grid, 64x32 each
  const int l15 = lane & 15;
  const int qw  = lane >> 4;                       // K-plane for fragment reads

  // XCD-chunked bijective swizzle (hardware id round-robins XCDs by linear id)
  const int nbx = gridDim.x;
  const int nwg = nbx * gridDim.y;
  int bid = blockIdx.y * nbx + blockIdx.x;
  {
    int q = nwg >> 3, r = nwg & 7;
    int xcd = bid & 7, idx = bid >> 3;
    bid = (xcd < r ? xcd * (q + 1) : r * (q + 1) + (xcd - r) * q) + idx;
  }
  const int row0 = (bid / nbx) * 128;
  const int col0 = (bid % nbx) * 64;
  const int Kend = K1 + K2;

  f32x4 acch[8], accl[8];
  #pragma unroll
  for (int i=0;i<8;i++){
    acch[i][0]=0.f; acch[i][1]=0.f; acch[i][2]=0.f; acch[i][3]=0.f;
    accl[i][0]=0.f; accl[i][1]=0.f; accl[i][2]=0.f; accl[i][3]=0.f;
  }

  for (int k0 = 0; k0 < Kp; k0 += 32) {
    #pragma unroll
    for (int t=0;t<2;t++){
      int idx = t*256 + tid;
      int r = idx >> 2, pl = idx & 3;
      int kg = k0 + pl*8;
      int grow = row0 + r;
      half8 v;
      #pragma unroll
      for (int q=0;q<8;q++) v[q] = (f16)0.f;
      if (grow < M){
        if (kg < K1)        v = *(const half8*)(A1 + (size_t)grow*lda1 + kg);
        else if (kg < Kend) v = *(const half8*)(A2 + (size_t)grow*lda2 + (kg - K1));
      }
      *(half8*)(&As[pl][r][0]) = v;
    }
    {
      int r = tid >> 2, pl = tid & 3;
      int kg = k0 + pl*8;
      *(half8*)(&Bh[pl][r][0]) = *(const half8*)(Bhi + (size_t)(col0 + r)*Kp + kg);
      *(half8*)(&Bl[pl][r][0]) = *(const half8*)(Blo + (size_t)(col0 + r)*Kp + kg);
    }
    __syncthreads();
    half8 af[4], bfh[2], bfl[2];
    #pragma unroll
    for (int mf=0; mf<4; mf++) af[mf] = *(const half8*)(&As[qw][wm*64 + mf*16 + l15][0]);
    #pragma unroll
    for (int nf=0; nf<2; nf++){
      bfh[nf] = *(const half8*)(&Bh[qw][wn*32 + nf*16 + l15][0]);
      bfl[nf] = *(const half8*)(&Bl[qw][wn*32 + nf*16 + l15][0]);
    }
    #pragma unroll
    for (int mf=0; mf<4; mf++)
      #pragma unroll
      for (int nf=0; nf<2; nf++){
        acch[mf*2+nf] = __builtin_amdgcn_mfma_f32_16x16x32_f16(af[mf], bfh[nf], acch[mf*2+nf], 0,0,0);
        accl[mf*2+nf] = __builtin_amdgcn_mfma_f32_16x16x32_f16(af[mf], bfl[nf], accl[mf*2+nf], 0,0,0);
      }
    __syncthreads();
  }

  // epilogue: C/D layout col=lane&15, row=(lane>>4)*4+reg
  #pragma unroll
  for (int mf=0; mf<4; mf++)
    #pragma unroll
    for (int nf=0; nf<2; nf++){
      int col  = col0 + wn*32 + nf*16 + l15;
      int rowb = row0 + wm*64 + mf*16 + (lane>>4)*4;
      float bi = bias ? bias[col] : 0.f;
      #pragma unroll
      for (int i=0;i<4;i++){
        int row = rowb + i;
        if (row >= M) continue;
        float r = acch[mf*2+nf][i] + accl[mf*2+nf][i] * (1.0f/2048.0f) + bi;
        if (mode == 1) r = fmaxf(r, 0.f);
        else if (mode == 2){
          r += (float)ep[(size_t)row*ldep + col];
          r = bn_elu(r, bng[col], bnb[col], bnm[col], bnv[col]);
        }
        C[(size_t)row*ldc + col] = (f16)r;
      }
    }
}

// ---------------- aggregation: online softmax over in-edges (fp16 I/O) ------
// PROJ row layout (stride ldp = 4*HC): [Q | K | V | QWE] each HC wide.
// att overwrites Q slice, SE overwrites QWE slice (own row only).
template<int HC>
__global__ __launch_bounds__(256)
void agg16_kernel(const int* __restrict__ rowptr, const int* __restrict__ csr_src,
                  f16* __restrict__ PROJ, int ldp, const f16* __restrict__ EFh, int nNodes)
{
  int lane = threadIdx.x & 63;
  int wid = (blockIdx.x * blockDim.x + threadIdx.x) >> 6;
  int grp = lane >> 4, l16 = lane & 15;
  int node, ch;
  if (HC == 256) { node = wid;          ch = 4*lane; }
  else           { node = wid*4 + grp;  ch = 4*l16;  }
  if (node >= nNodes) return;
  f16* rowp = PROJ + (size_t)node*ldp;
  half4v qh = *(const half4v*)(rowp + ch);
  half4v wh = *(const half4v*)(rowp + 3*HC + ch);
  float q0=qh[0],q1=qh[1],q2=qh[2],q3=qh[3];
  float w0=wh[0],w1=wh[1],w2=wh[2],w3=wh[3];
  int e0 = rowptr[node], e1 = rowptr[node+1];

  float m = -INFINITY, den = 0.f;
  float avx=0.f,avy=0.f,avz=0.f,avw=0.f, aex=0.f,aey=0.f,aez=0.f,aew=0.f;

  for (int i = e0; i < e1; ++i) {
    int s = csr_src[i];
    const f16* srow = PROJ + (size_t)s*ldp;
    half4v k4 = *(const half4v*)(srow + HC + ch);
    half4v e4 = *(const half4v*)(EFh + (size_t)i*64 + 4*l16);
    float ex=e4[0], ey=e4[1], ez=e4[2], ew=e4[3];
    float p = q0*(float)k4[0] + q1*(float)k4[1] + q2*(float)k4[2] + q3*(float)k4[3]
            + w0*ex + w1*ey + w2*ez + w3*ew;
    p += __shfl_xor(p, 1);
    p += __shfl_xor(p, 2);
    p += __shfl_xor(p, 4);
    p += __shfl_xor(p, 8);
    float alpha = p * 0.125f;       // 1/sqrt(64)
    float mn = fmaxf(m, alpha);
    float sc = __expf(m - mn);      // -inf -> 0 on first edge
    float w  = __expf(alpha - mn);
    half4v v4 = *(const half4v*)(srow + 2*HC + ch);
    den = den*sc + w;
    avx = avx*sc + w*(float)v4[0]; avy = avy*sc + w*(float)v4[1];
    avz = avz*sc + w*(float)v4[2]; avw = avw*sc + w*(float)v4[3];
    aex = aex*sc + w*ex; aey = aey*sc + w*ey;
    aez = aez*sc + w*ez; aew = aew*sc + w*ew;
    m = mn;
  }
  float inv = den > 0.f ? 1.0f/den : 0.f;
  half4v o1, o2;
  o1[0]=(f16)(avx*inv); o1[1]=(f16)(avy*inv); o1[2]=(f16)(avz*inv); o1[3]=(f16)(avw*inv);
  o2[0]=(f16)(aex*inv); o2[1]=(f16)(aey*inv); o2[2]=(f16)(aez*inv); o2[3]=(f16)(aew*inv);
  *(half4v*)(rowp + ch) = o1;
  *(half4v*)(rowp + 3*HC + ch) = o2;
}

// ---------------- mean pool (batch sorted, fp16 in) ----------------
__global__ void pool16_kernel(const f16* __restrict__ Hf, const int* __restrict__ batch,
                              float* __restrict__ gsum, int nNodes){
  const int CH = 64;
  int c = threadIdx.x & 63;
  int chunk = blockIdx.x * (blockDim.x >> 6) + (threadIdx.x >> 6);
  int n0 = chunk * CH;
  if (n0 >= nNodes) return;
  int n1 = min(n0 + CH, nNodes);
  float acc = 0.f;
  int g = batch[n0];
  for (int n = n0; n < n1; ++n) {
    int gn = batch[n];
    if (gn != g) { atomicAdd(&gsum[g*64 + c], acc); acc = 0.f; g = gn; }
    acc += (float)Hf[(size_t)n*64 + c];
  }
  atomicAdd(&gsum[g*64 + c], acc);
}

// ---------------- MLP head (fp32) ----------------
__global__ void mlp_kernel(const float* __restrict__ gsum, const int* __restrict__ batch,
                           int nNodes, int G,
                           const float* __restrict__ w1, const float* __restrict__ b1,
                           const float* __restrict__ w2, const float* __restrict__ b2,
                           const float* __restrict__ w3, const float* __restrict__ b3,
                           float* __restrict__ out){
  int g = threadIdx.x;
  if (g >= G) return;
  int lo = 0, hi = nNodes;
  while (lo < hi){ int mid = (lo+hi)>>1; if (batch[mid] < g) lo = mid+1; else hi = mid; }
  int first = lo;
  lo = 0; hi = nNodes;
  while (lo < hi){ int mid = (lo+hi)>>1; if (batch[mid] < g+1) lo = mid+1; else hi = mid; }
  int cnt = lo - first;
  float invc = 1.0f / fmaxf((float)cnt, 1.0f);
  float gm[64];
  #pragma unroll
  for (int c = 0; c < 64; ++c) gm[c] = gsum[g*64 + c] * invc;
  float r1[32];
  for (int j = 0; j < 32; ++j){
    float s = b1[j];
    for (int c = 0; c < 64; ++c) s = fmaf(gm[c], w1[c*32 + j], s);
    r1[j] = fmaxf(s, 0.f);
  }
  float r2[16];
  for (int j = 0; j < 16; ++j){
    float s = b2[j];
    for (int c = 0; c < 32; ++c) s = fmaf(r1[c], w2[c*16 + j], s);
    r2[j] = fmaxf(s, 0.f);
  }
  float s = b3[0];
  for (int c = 0; c < 16; ++c) s = fmaf(r2[c], w3[c], s);
  out[g] = s;
}

// ---------------------------------------------------------------------------
static inline void launch_hgemm(hipStream_t st,
    const f16* A1, int lda1, int K1, const f16* A2, int lda2, int K2,
    const f16* Bhi, const f16* Blo, int Kp, const float* bias,
    f16* C, int ldc, int M, int Ncols, int mode,
    const f16* ep, int ldep,
    const float* g, const float* b, const float* m, const float* v)
{
  dim3 grid(Ncols / 64, (M + 127) / 128, 1);   // col blocks fastest
  hgemm_kernel<<<grid, 256, 0, st>>>(A1, lda1, K1, A2, lda2, K2, Bhi, Blo, Kp,
                                     bias, C, ldc, M, mode, ep, ldep, g, b, m, v);
}

struct ConvW {
  const float *wq,*bq,*wk,*bk,*wv,*bv,*we,*ws,*bs,*bg,*bb,*bm,*bv_;
};

extern "C" void kernel_launch(void* const* d_in, const int* in_sizes, int n_in,
                              void* d_out, int out_size, void* d_ws, size_t ws_size,
                              hipStream_t stream) {
  (void)n_in;
  const float* x     = (const float*)d_in[0];
  const int*   ei    = (const int*)d_in[1];
  const float* eattr = (const float*)d_in[2];
  const int*   batch = (const int*)d_in[3];
  const float* ee_w1 = (const float*)d_in[4];
  const float* ee_b1 = (const float*)d_in[5];
  const float* ee_w2 = (const float*)d_in[6];
  const float* ee_b2 = (const float*)d_in[7];
  ConvW cw[3];
  {
    int t = 8;
    for (int c = 0; c < 3; ++c){
      cw[c].wq=(const float*)d_in[t++]; cw[c].bq=(const float*)d_in[t++];
      cw[c].wk=(const float*)d_in[t++]; cw[c].bk=(const float*)d_in[t++];
      cw[c].wv=(const float*)d_in[t++]; cw[c].bv=(const float*)d_in[t++];
      cw[c].we=(const float*)d_in[t++]; cw[c].ws=(const float*)d_in[t++]; cw[c].bs=(const float*)d_in[t++];
    }
    for (int c = 0; c < 3; ++c){
      cw[c].bg=(const float*)d_in[t++]; cw[c].bb=(const float*)d_in[t++];
      cw[c].bm=(const float*)d_in[t++]; cw[c].bv_=(const float*)d_in[t++];
    }
  }
  const float* r_w1 = (const float*)d_in[47];
  const float* r_b1 = (const float*)d_in[48];
  const float* r_w2 = (const float*)d_in[49];
  const float* r_b2 = (const float*)d_in[50];
  const float* r_w3 = (const float*)d_in[51];
  const float* r_b3 = (const float*)d_in[52];

  const int N = in_sizes[0] / 64;      // 50000
  const int E = in_sizes[2] / 16;      // 400000
  const int G = out_size;              // 128

  // ---- workspace layout ----
  char* wp = (char*)d_ws;
  f16* HA   = (f16*)wp;            wp += (size_t)N*256*2;   // 25.6 MB
  f16* HB   = (f16*)wp;            wp += (size_t)N*256*2;   // 25.6 MB
  f16* PROJ = (f16*)wp;            wp += (size_t)N*1024*2;  // 102.4 MB
  f16* EFh  = (f16*)wp;            wp += (size_t)E*64*2;    // 51.2 MB
  f16* Bhi  = (f16*)wp;            wp += 262144*2;          // 512 KB
  f16* Blo  = (f16*)wp;            wp += 262144*2;          // 512 KB
  float* WqeS  = (float*)wp;       wp += 65536*4;           // 256 KB
  float* biasP = (float*)wp;       wp += 1024*4;
  float* gsum  = (float*)wp;       wp += 8192*4;
  int* ideg  = (int*)wp;           wp += (size_t)N*4;
  int* icnt  = (int*)wp;           wp += (size_t)N*4;
  int* irow  = (int*)wp;           wp += (size_t)(N+1)*4;
  int* csr_s = (int*)wp;           wp += (size_t)E*4;
  int* csr_e = (int*)wp;           wp += (size_t)E*4;
  size_t used = (size_t)(wp - (char*)d_ws);
  if (used > ws_size) {
    leak_kernel<<<(G + 255)/256, 256, 0, stream>>>((float*)d_out, G, (float)(ws_size >> 20));
    return;
  }
  // encoder-phase aliases (dead before convs):
  f16* EA16  = HA;                 // [E,16]  6.4M halves <= 12.8M
  f16* HID   = PROJ;               // [E,64]  25.6M halves
  f16* EFtmp = PROJ + (size_t)E*64;// [E,64]  25.6M halves (PROJ total 51.2M)

  const int* src = ei;
  const int* dst = ei + E;

  // ---- zero gsum/deg/cnt (contiguous) ----
  zero_kernel<<<(8192 + 2*N + 255)/256, 256, 0, stream>>>((int*)gsum, 8192 + 2*N);

  // ---- CSR by dst ----
  hist_kernel<<<(E + 255)/256, 256, 0, stream>>>(dst, ideg, E);
  scan_kernel<<<1, 1024, 0, stream>>>(ideg, irow, N);
  scatter_kernel<<<(E + 255)/256, 256, 0, stream>>>(src, dst, irow, icnt, csr_s, csr_e, E);

  // ---- edge encoder (fp16 MFMA): e = relu(ea@W1+b1)@W2+b2 ----
  cvt16_kernel<<<(E*16 + 255)/256, 256, 0, stream>>>(eattr, EA16, E*16);
  packB_kernel<<<(64*32 + 255)/256, 256, 0, stream>>>(ee_w1, 64, 16, 64, 0, Bhi, Blo, 32);
  launch_hgemm(stream, EA16, 16, 16, nullptr, 0, 0, Bhi, Blo, 32, ee_b1,
               HID, 64, E, 64, 1, nullptr, 0, 0,0,0,0);
  packB_kernel<<<(64*64 + 255)/256, 256, 0, stream>>>(ee_w2, 64, 64, 64, 0, Bhi, Blo, 64);
  launch_hgemm(stream, HID, 64, 64, nullptr, 0, 0, Bhi, Blo, 64, ee_b2,
               EFtmp, 64, E, 64, 0, nullptr, 0, 0,0,0,0);
  gather_ef16_kernel<<<(E*8 + 255)/256, 256, 0, stream>>>(EFtmp, csr_e, EFh, E);

  // ---- x -> fp16 (EA16 dead now) ----
  cvt16_kernel<<<(N*64 + 255)/256, 256, 0, stream>>>(x, HA, N*64);

  // ================= conv layers =================
  for (int c = 0; c < 3; ++c) {
    const int din = (c == 0) ? 64 : 256;
    const int H   = (c == 2) ? 1 : 4;
    const int hc  = H * 64;
    const int ldp = 4 * hc;
    const f16* Xin = (c == 0) ? HA : ((c == 1) ? HB : HA);
    const int  ldx = (c == 0) ? 64 : 256;
    f16* Hout = (c == 1) ? HA : HB;
    const ConvW& W = cw[c];

    // combined qwe weights + packed proj B = [Wq|Wk|Wv|Wqe], bias = [bq|bk|bv|bqe]
    wqe_kernel<<<((din+1)*hc + 255)/256, 256, 0, stream>>>(W.wq, W.bq, W.we, WqeS, biasP + 3*hc, din, H);
    int Kp = din;  // din is 64 or 256, both mult of 32
    packB_kernel<<<(hc*Kp + 255)/256, 256, 0, stream>>>(W.wq, hc, din, hc, 0,    Bhi, Blo, Kp);
    packB_kernel<<<(hc*Kp + 255)/256, 256, 0, stream>>>(W.wk, hc, din, hc, hc,   Bhi, Blo, Kp);
    packB_kernel<<<(hc*Kp + 255)/256, 256, 0, stream>>>(W.wv, hc, din, hc, 2*hc, Bhi, Blo, Kp);
    packB_kernel<<<(hc*Kp + 255)/256, 256, 0, stream>>>(WqeS, hc, din, hc, 3*hc, Bhi, Blo, Kp);
    copyf_kernel<<<(hc + 255)/256, 256, 0, stream>>>(biasP,        W.bq, hc);
    copyf_kernel<<<(hc + 255)/256, 256, 0, stream>>>(biasP + hc,   W.bk, hc);
    copyf_kernel<<<(hc + 255)/256, 256, 0, stream>>>(biasP + 2*hc, W.bv, hc);

    // fused projection: PROJ = Xin @ [Wq|Wk|Wv|Wqe] + biasP   [N, 4*hc] fp16
    launch_hgemm(stream, Xin, ldx, din, nullptr, 0, 0, Bhi, Blo, Kp, biasP,
                 PROJ, ldp, N, 4*hc, 0, nullptr, 0, 0,0,0,0);

    // aggregation (att -> Q slice, SE -> QWE slice)
    if (H == 4) agg16_kernel<256><<<(N + 3)/4,  256, 0, stream>>>(irow, csr_s, PROJ, ldp, EFh, N);
    else        agg16_kernel<64> <<<(N + 15)/16,256, 0, stream>>>(irow, csr_s, PROJ, ldp, EFh, N);

    // post: Hout = BN_ELU( [SE | Xin] @ [blockdiag(we); ws] + bs + att )
    int Kpp = hc + din;  // 320, 512, 320 -- all mult of 32
    packBpost_kernel<<<(hc*Kpp + 255)/256, 256, 0, stream>>>(W.we, W.ws, din, hc, Bhi, Blo, Kpp);
    launch_hgemm(stream, PROJ + 3*hc, ldp, hc, Xin, ldx, din, Bhi, Blo, Kpp, W.bs,
                 Hout, hc, N, hc, 2, PROJ, ldp, W.bg, W.bb, W.bm, W.bv_);
  }

  // ---- global mean pool + MLP ----
  {
    int chunks = (N + 63) / 64;
    pool16_kernel<<<(chunks + 3)/4, 256, 0, stream>>>(HB, batch, gsum, N);
  }
  mlp_kernel<<<1, 128, 0, stream>>>(gsum, batch, N, G, r_w1, r_b1, r_w2, r_b2, r_w3, r_b3,
                                    (float*)d_out);
}

// Round 6
// 961.331 us; speedup vs baseline: 2.1584x; 1.0978x over previous
//
#include <hip/hip_runtime.h>
#include <math.h>

// ---------------------------------------------------------------------------
// GTR_50139448214076: 3x TransformerConv GNN + BN/ELU + mean-pool + MLP
// All GEMMs on MFMA fp16 (split-weight hi + lo/2048), activations fp16,
// fp32 accumulation. Per conv: ONE fused projection GEMM X@[Wq|Wk|Wv|Wqe],
// wave-per-node online-softmax aggregation, post GEMM [SE|X]@[bd(we);ws].
// R6: global_load_lds staging with pre-swizzled global source; XOR chunk
//     swizzle c^=((r>>2)&3) -> conflict-free ds_read_b128 fragment reads.
//     XCD-chunked bijective block swizzle kept (FETCH 209->17MB proven).
// ---------------------------------------------------------------------------

typedef _Float16 f16;
typedef _Float16 half8  __attribute__((ext_vector_type(8)));
typedef _Float16 half4v __attribute__((ext_vector_type(4)));
typedef float    f32x4  __attribute__((ext_vector_type(4)));

__device__ __forceinline__ void gload16(const void* g, void* l){
  __builtin_amdgcn_global_load_lds((const __attribute__((address_space(1))) void*)g,
                                   (__attribute__((address_space(3))) void*)l, 16, 0, 0);
}

// ---------------- utility ----------------
__global__ void zero_kernel(int* __restrict__ p, int n){
  int i = blockIdx.x*blockDim.x + threadIdx.x;
  if (i < n) p[i] = 0;
}
__global__ void leak_kernel(float* __restrict__ out, int n, float val){
  int i = blockIdx.x*blockDim.x + threadIdx.x;
  if (i < n) out[i] = val;
}
__global__ void copyf_kernel(float* __restrict__ dst, const float* __restrict__ src, int n){
  int i = blockIdx.x*blockDim.x + threadIdx.x;
  if (i < n) dst[i] = src[i];
}
__global__ void cvt16_kernel(const float* __restrict__ src, f16* __restrict__ dst, int n){
  int i = blockIdx.x*blockDim.x + threadIdx.x;
  if (i < n) dst[i] = (f16)src[i];
}

// ---------------- CSR build ----------------
__global__ void hist_kernel(const int* __restrict__ dst, int* __restrict__ deg, int E){
  int i = blockIdx.x*blockDim.x + threadIdx.x;
  if (i < E) atomicAdd(&deg[dst[i]], 1);
}

__global__ __launch_bounds__(1024)
void scan_kernel(const int* __restrict__ deg, int* __restrict__ rowptr, int n){
  __shared__ int buf[1024];
  __shared__ int sbase;
  int tid = threadIdx.x;
  if (tid == 0){ sbase = 0; rowptr[0] = 0; }
  __syncthreads();
  for (int start = 0; start < n; start += 4096){
    int i0 = start + tid*4;
    int a0 = (i0+0<n)?deg[i0+0]:0;
    int a1 = (i0+1<n)?deg[i0+1]:0;
    int a2 = (i0+2<n)?deg[i0+2]:0;
    int a3 = (i0+3<n)?deg[i0+3]:0;
    int s = a0+a1+a2+a3;
    int v = s;
    buf[tid] = v;
    __syncthreads();
    for (int off=1; off<1024; off<<=1){
      int t = (tid >= off) ? buf[tid-off] : 0;
      __syncthreads();
      v += t;
      buf[tid] = v;
      __syncthreads();
    }
    int pre = sbase + v - s;
    if (i0+0 < n) rowptr[i0+1] = pre + a0;
    if (i0+1 < n) rowptr[i0+2] = pre + a0 + a1;
    if (i0+2 < n) rowptr[i0+3] = pre + a0 + a1 + a2;
    if (i0+3 < n) rowptr[i0+4] = pre + s;
    __syncthreads();
    if (tid == 1023) sbase += buf[1023];
    __syncthreads();
  }
}

__global__ void scatter_kernel(const int* __restrict__ src, const int* __restrict__ dst,
                               const int* __restrict__ rowptr, int* __restrict__ cnt,
                               int* __restrict__ csr_src, int* __restrict__ csr_eid, int E){
  int i = blockIdx.x*blockDim.x + threadIdx.x;
  if (i >= E) return;
  int d = dst[i];
  int pos = rowptr[d] + atomicAdd(&cnt[d], 1);
  csr_src[pos] = src[i];
  csr_eid[pos] = i;
}

// EFh[i] = EFt[csr_eid[i]]  (fp16 edge features -> CSR order)
__global__ void gather_ef16_kernel(const f16* __restrict__ EFt, const int* __restrict__ csr_eid,
                                   f16* __restrict__ EFh, int E){
  int i = blockIdx.x*blockDim.x + threadIdx.x;   // E*8 chunks of 8 halves
  if (i >= E*8) return;
  int e = i >> 3, j8 = (i & 7) * 8;
  *(half8*)(EFh + (size_t)e*64 + j8) = *(const half8*)(EFt + (size_t)csr_eid[e]*64 + j8);
}

// ---------------- weight prep ----------------
// Wqe[d, h*64+j] = sum_c wq[d,h*64+c]*we[j,h*64+c];  bqe likewise from bq.
__global__ void wqe_kernel(const float* __restrict__ wq, const float* __restrict__ bq,
                           const float* __restrict__ we, float* __restrict__ Wqe,
                           float* __restrict__ bqe, int din, int H){
  int hc = H*64;
  int i = blockIdx.x*blockDim.x + threadIdx.x;
  if (i >= (din+1)*hc) return;
  int d = i / hc, col = i - d*hc;
  int h = col >> 6, j = col & 63;
  const float* qsub = ((d < din) ? (wq + (size_t)d*hc) : bq) + h*64;
  const float* wrow = we + (size_t)j*hc + h*64;
  float s = 0.f;
  #pragma unroll 8
  for (int c = 0; c < 64; ++c) s += qsub[c] * wrow[c];
  if (d < din) Wqe[(size_t)d*hc + col] = s;
  else bqe[col] = s;
}

// pack fp32 src[K, Csub] (row stride lds) into B^T hi/lo [coloff+c][Kp], zero-pad k>=K
__global__ void packB_kernel(const float* __restrict__ src, int lds, int K, int Csub, int coloff,
                             f16* __restrict__ Bhi, f16* __restrict__ Blo, int Kp){
  int i = blockIdx.x*blockDim.x + threadIdx.x;
  if (i >= Csub*Kp) return;
  int c = i / Kp, k = i - c*Kp;
  float v = (k < K) ? src[(size_t)k*lds + c] : 0.f;
  f16 hi = (f16)v;
  f16 lo = (f16)((v - (float)hi) * 2048.0f);
  Bhi[(size_t)(coloff+c)*Kp + k] = hi;
  Blo[(size_t)(coloff+c)*Kp + k] = lo;
}

// B^T pack for post GEMM: k<hc -> blockdiag(we) (head-matched), k in [hc,hc+din) -> ws
__global__ void packBpost_kernel(const float* __restrict__ we, const float* __restrict__ ws,
                                 int din, int hc,
                                 f16* __restrict__ Bhi, f16* __restrict__ Blo, int Kp){
  int i = blockIdx.x*blockDim.x + threadIdx.x;
  if (i >= hc*Kp) return;
  int c = i / Kp, k = i - c*Kp;
  float v = 0.f;
  if (k < hc) { if ((k>>6) == (c>>6)) v = we[(size_t)(k&63)*hc + c]; }
  else if (k < hc + din) v = ws[(size_t)(k-hc)*hc + c];
  f16 hi = (f16)v;
  f16 lo = (f16)((v - (float)hi) * 2048.0f);
  Bhi[(size_t)c*Kp + k] = hi;
  Blo[(size_t)c*Kp + k] = lo;
}

// ---------------- MFMA fp16 GEMM (split-weight, gload_lds + XOR swizzle) ----
// C[M, Ncols] = [A1 | A2] @ (Bhi + Blo/2048) + bias, optional epilogues.
// Grid: (Ncols/64, ceil(M/128)). LDS element (row r, chunk c) holds global
// chunk c ^ ((r>>2)&3); staged via per-lane pre-swizzled global source.
// A sources MUST be readable for 128 rows past M (padded workspace).
// mode 0: +bias; 1: +bias,relu; 2: +bias +ep(f16) +BN +ELU. Output fp16.
__device__ __forceinline__ float bn_elu(float x, float g, float b, float m, float v){
  float s = g / sqrtf(v + 1e-5f);
  float y = (x - m) * s + b;
  return y > 0.f ? y : expm1f(y);
}

__global__ __launch_bounds__(256)
void hgemm_kernel(const f16* __restrict__ A1, int lda1, int K1,
                  const f16* __restrict__ A2, int lda2, int K2,
                  const f16* __restrict__ Bhi, const f16* __restrict__ Blo, int Kp,
                  const float* __restrict__ bias,
                  f16* __restrict__ C, int ldc, int M, int mode,
                  const f16* __restrict__ ep, int ldep,
                  const float* __restrict__ bng, const float* __restrict__ bnb,
                  const float* __restrict__ bnm, const float* __restrict__ bnv)
{
  __shared__ f16 As[128*32];
  __shared__ f16 Bh[64*32];
  __shared__ f16 Bl[64*32];
  const int tid  = threadIdx.x;
  const int lane = tid & 63;
  const int wave = tid >> 6;
  const int wm = wave >> 1, wn = wave & 1;       // 2x2 wave grid, 64x32 each
  const int l15 = lane & 15;
  const int cs  = (lane >> 4) ^ ((lane >> 2) & 3);   // fragment-read chunk
  const int csl = (lane & 3) ^ (lane >> 4);          // staging source chunk
  const int arow = lane >> 2;                        // staging row-in-group

  // XCD-chunked bijective swizzle (hardware id round-robins XCDs by linear id)
  const int nbx = gridDim.x;
  const int nwg = nbx * gridDim.y;
  int bid = blockIdx.y * nbx + blockIdx.x;
  {
    int q = nwg >> 3, r = nwg & 7;
    int xcd = bid & 7, idx = bid >> 3;
    bid = (xcd < r ? xcd * (q + 1) : r * (q + 1) + (xcd - r) * q) + idx;
  }
  const int row0 = (bid / nbx) * 128;
  const int col0 = (bid % nbx) * 64;

  f32x4 acch[8], accl[8];
  #pragma unroll
  for (int i=0;i<8;i++){
    acch[i][0]=0.f; acch[i][1]=0.f; acch[i][2]=0.f; acch[i][3]=0.f;
    accl[i][0]=0.f; accl[i][1]=0.f; accl[i][2]=0.f; accl[i][3]=0.f;
  }

  for (int k0 = 0; k0 < Kp; k0 += 32) {
    // select A source for this K-window (K1 is a multiple of 32)
    const f16* Ap; int lda, ks;
    if (k0 < K1) { Ap = A1; lda = lda1; ks = k0; }
    else         { Ap = A2; lda = lda2; ks = k0 - K1; }
    // stage A: wave handles rows [wave*32, wave*32+32), 2 issues of 16 rows
    #pragma unroll
    for (int t = 0; t < 2; ++t) {
      int r = wave*32 + t*16 + arow;
      const f16* gp = Ap + (size_t)(row0 + r)*lda + ks + csl*8;
      gload16(gp, As + (wave*32 + t*16)*32);
    }
    // stage B: wave handles cols [wave*16, wave*16+16)
    {
      int r = wave*16 + arow;
      const f16* gbh = Bhi + (size_t)(col0 + r)*Kp + k0 + csl*8;
      const f16* gbl = Blo + (size_t)(col0 + r)*Kp + k0 + csl*8;
      gload16(gbh, Bh + wave*16*32);
      gload16(gbl, Bl + wave*16*32);
    }
    __syncthreads();   // drains vmcnt (compiler emits s_waitcnt vmcnt(0))

    half8 af[4], bfh[2], bfl[2];
    #pragma unroll
    for (int mf=0; mf<4; mf++)
      af[mf] = *(const half8*)(As + (wm*64 + mf*16 + l15)*32 + cs*8);
    #pragma unroll
    for (int nf=0; nf<2; nf++){
      bfh[nf] = *(const half8*)(Bh + (wn*32 + nf*16 + l15)*32 + cs*8);
      bfl[nf] = *(const half8*)(Bl + (wn*32 + nf*16 + l15)*32 + cs*8);
    }
    #pragma unroll
    for (int mf=0; mf<4; mf++)
      #pragma unroll
      for (int nf=0; nf<2; nf++){
        acch[mf*2+nf] = __builtin_amdgcn_mfma_f32_16x16x32_f16(af[mf], bfh[nf], acch[mf*2+nf], 0,0,0);
        accl[mf*2+nf] = __builtin_amdgcn_mfma_f32_16x16x32_f16(af[mf], bfl[nf], accl[mf*2+nf], 0,0,0);
      }
    __syncthreads();
  }

  // epilogue: C/D layout col=lane&15, row=(lane>>4)*4+reg
  #pragma unroll
  for (int mf=0; mf<4; mf++)
    #pragma unroll
    for (int nf=0; nf<2; nf++){
      int col  = col0 + wn*32 + nf*16 + l15;
      int rowb = row0 + wm*64 + mf*16 + (lane>>4)*4;
      float bi = bias ? bias[col] : 0.f;
      #pragma unroll
      for (int i=0;i<4;i++){
        int row = rowb + i;
        if (row >= M) continue;
        float r = acch[mf*2+nf][i] + accl[mf*2+nf][i] * (1.0f/2048.0f) + bi;
        if (mode == 1) r = fmaxf(r, 0.f);
        else if (mode == 2){
          r += (float)ep[(size_t)row*ldep + col];
          r = bn_elu(r, bng[col], bnb[col], bnm[col], bnv[col]);
        }
        C[(size_t)row*ldc + col] = (f16)r;
      }
    }
}

// ---------------- aggregation: online softmax over in-edges (fp16 I/O) ------
// PROJ row layout (stride ldp = 4*HC): [Q | K | V | QWE] each HC wide.
// att overwrites Q slice, SE overwrites QWE slice (own row only).
template<int HC>
__global__ __launch_bounds__(256)
void agg16_kernel(const int* __restrict__ rowptr, const int* __restrict__ csr_src,
                  f16* __restrict__ PROJ, int ldp, const f16* __restrict__ EFh, int nNodes)
{
  int lane = threadIdx.x & 63;
  int wid = (blockIdx.x * blockDim.x + threadIdx.x) >> 6;
  int grp = lane >> 4, l16 = lane & 15;
  int node, ch;
  if (HC == 256) { node = wid;          ch = 4*lane; }
  else           { node = wid*4 + grp;  ch = 4*l16;  }
  if (node >= nNodes) return;
  f16* rowp = PROJ + (size_t)node*ldp;
  half4v qh = *(const half4v*)(rowp + ch);
  half4v wh = *(const half4v*)(rowp + 3*HC + ch);
  float q0=qh[0],q1=qh[1],q2=qh[2],q3=qh[3];
  float w0=wh[0],w1=wh[1],w2=wh[2],w3=wh[3];
  int e0 = rowptr[node], e1 = rowptr[node+1];

  float m = -INFINITY, den = 0.f;
  float avx=0.f,avy=0.f,avz=0.f,avw=0.f, aex=0.f,aey=0.f,aez=0.f,aew=0.f;

  for (int i = e0; i < e1; ++i) {
    int s = csr_src[i];
    const f16* srow = PROJ + (size_t)s*ldp;
    half4v k4 = *(const half4v*)(srow + HC + ch);
    half4v e4 = *(const half4v*)(EFh + (size_t)i*64 + 4*l16);
    float ex=e4[0], ey=e4[1], ez=e4[2], ew=e4[3];
    float p = q0*(float)k4[0] + q1*(float)k4[1] + q2*(float)k4[2] + q3*(float)k4[3]
            + w0*ex + w1*ey + w2*ez + w3*ew;
    p += __shfl_xor(p, 1);
    p += __shfl_xor(p, 2);
    p += __shfl_xor(p, 4);
    p += __shfl_xor(p, 8);
    float alpha = p * 0.125f;       // 1/sqrt(64)
    float mn = fmaxf(m, alpha);
    float sc = __expf(m - mn);      // -inf -> 0 on first edge
    float w  = __expf(alpha - mn);
    half4v v4 = *(const half4v*)(srow + 2*HC + ch);
    den = den*sc + w;
    avx = avx*sc + w*(float)v4[0]; avy = avy*sc + w*(float)v4[1];
    avz = avz*sc + w*(float)v4[2]; avw = avw*sc + w*(float)v4[3];
    aex = aex*sc + w*ex; aey = aey*sc + w*ey;
    aez = aez*sc + w*ez; aew = aew*sc + w*ew;
    m = mn;
  }
  float inv = den > 0.f ? 1.0f/den : 0.f;
  half4v o1, o2;
  o1[0]=(f16)(avx*inv); o1[1]=(f16)(avy*inv); o1[2]=(f16)(avz*inv); o1[3]=(f16)(avw*inv);
  o2[0]=(f16)(aex*inv); o2[1]=(f16)(aey*inv); o2[2]=(f16)(aez*inv); o2[3]=(f16)(aew*inv);
  *(half4v*)(rowp + ch) = o1;
  *(half4v*)(rowp + 3*HC + ch) = o2;
}

// ---------------- mean pool (batch sorted, fp16 in) ----------------
__global__ void pool16_kernel(const f16* __restrict__ Hf, const int* __restrict__ batch,
                              float* __restrict__ gsum, int nNodes){
  const int CH = 64;
  int c = threadIdx.x & 63;
  int chunk = blockIdx.x * (blockDim.x >> 6) + (threadIdx.x >> 6);
  int n0 = chunk * CH;
  if (n0 >= nNodes) return;
  int n1 = min(n0 + CH, nNodes);
  float acc = 0.f;
  int g = batch[n0];
  for (int n = n0; n < n1; ++n) {
    int gn = batch[n];
    if (gn != g) { atomicAdd(&gsum[g*64 + c], acc); acc = 0.f; g = gn; }
    acc += (float)Hf[(size_t)n*64 + c];
  }
  atomicAdd(&gsum[g*64 + c], acc);
}

// ---------------- MLP head (fp32) ----------------
__global__ void mlp_kernel(const float* __restrict__ gsum, const int* __restrict__ batch,
                           int nNodes, int G,
                           const float* __restrict__ w1, const float* __restrict__ b1,
                           const float* __restrict__ w2, const float* __restrict__ b2,
                           const float* __restrict__ w3, const float* __restrict__ b3,
                           float* __restrict__ out){
  int g = threadIdx.x;
  if (g >= G) return;
  int lo = 0, hi = nNodes;
  while (lo < hi){ int mid = (lo+hi)>>1; if (batch[mid] < g) lo = mid+1; else hi = mid; }
  int first = lo;
  lo = 0; hi = nNodes;
  while (lo < hi){ int mid = (lo+hi)>>1; if (batch[mid] < g+1) lo = mid+1; else hi = mid; }
  int cnt = lo - first;
  float invc = 1.0f / fmaxf((float)cnt, 1.0f);
  float gm[64];
  #pragma unroll
  for (int c = 0; c < 64; ++c) gm[c] = gsum[g*64 + c] * invc;
  float r1[32];
  for (int j = 0; j < 32; ++j){
    float s = b1[j];
    for (int c = 0; c < 64; ++c) s = fmaf(gm[c], w1[c*32 + j], s);
    r1[j] = fmaxf(s, 0.f);
  }
  float r2[16];
  for (int j = 0; j < 16; ++j){
    float s = b2[j];
    for (int c = 0; c < 32; ++c) s = fmaf(r1[c], w2[c*16 + j], s);
    r2[j] = fmaxf(s, 0.f);
  }
  float s = b3[0];
  for (int c = 0; c < 16; ++c) s = fmaf(r2[c], w3[c], s);
  out[g] = s;
}

// ---------------------------------------------------------------------------
static inline void launch_hgemm(hipStream_t st,
    const f16* A1, int lda1, int K1, const f16* A2, int lda2, int K2,
    const f16* Bhi, const f16* Blo, int Kp, const float* bias,
    f16* C, int ldc, int M, int Ncols, int mode,
    const f16* ep, int ldep,
    const float* g, const float* b, const float* m, const float* v)
{
  dim3 grid(Ncols / 64, (M + 127) / 128, 1);   // col blocks fastest
  hgemm_kernel<<<grid, 256, 0, st>>>(A1, lda1, K1, A2, lda2, K2, Bhi, Blo, Kp,
                                     bias, C, ldc, M, mode, ep, ldep, g, b, m, v);
}

struct ConvW {
  const float *wq,*bq,*wk,*bk,*wv,*bv,*we,*ws,*bs,*bg,*bb,*bm,*bv_;
};

extern "C" void kernel_launch(void* const* d_in, const int* in_sizes, int n_in,
                              void* d_out, int out_size, void* d_ws, size_t ws_size,
                              hipStream_t stream) {
  (void)n_in;
  const float* x     = (const float*)d_in[0];
  const int*   ei    = (const int*)d_in[1];
  const float* eattr = (const float*)d_in[2];
  const int*   batch = (const int*)d_in[3];
  const float* ee_w1 = (const float*)d_in[4];
  const float* ee_b1 = (const float*)d_in[5];
  const float* ee_w2 = (const float*)d_in[6];
  const float* ee_b2 = (const float*)d_in[7];
  ConvW cw[3];
  {
    int t = 8;
    for (int c = 0; c < 3; ++c){
      cw[c].wq=(const float*)d_in[t++]; cw[c].bq=(const float*)d_in[t++];
      cw[c].wk=(const float*)d_in[t++]; cw[c].bk=(const float*)d_in[t++];
      cw[c].wv=(const float*)d_in[t++]; cw[c].bv=(const float*)d_in[t++];
      cw[c].we=(const float*)d_in[t++]; cw[c].ws=(const float*)d_in[t++]; cw[c].bs=(const float*)d_in[t++];
    }
    for (int c = 0; c < 3; ++c){
      cw[c].bg=(const float*)d_in[t++]; cw[c].bb=(const float*)d_in[t++];
      cw[c].bm=(const float*)d_in[t++]; cw[c].bv_=(const float*)d_in[t++];
    }
  }
  const float* r_w1 = (const float*)d_in[47];
  const float* r_b1 = (const float*)d_in[48];
  const float* r_w2 = (const float*)d_in[49];
  const float* r_b2 = (const float*)d_in[50];
  const float* r_w3 = (const float*)d_in[51];
  const float* r_b3 = (const float*)d_in[52];

  const int N = in_sizes[0] / 64;      // 50000
  const int E = in_sizes[2] / 16;      // 400000
  const int G = out_size;              // 128

  // ---- workspace layout (A-source buffers padded by 128 rows for gload) ----
  const size_t NPAD = (size_t)N + 128;
  char* wp = (char*)d_ws;
  f16* HA   = (f16*)wp;            wp += NPAD*256*2;        // ~25.7 MB
  f16* HB   = (f16*)wp;            wp += NPAD*256*2;        // ~25.7 MB
  f16* PROJ = (f16*)wp;            wp += NPAD*1024*2;       // ~102.7 MB
  f16* EFh  = (f16*)wp;            wp += (size_t)E*64*2;    // 51.2 MB
  f16* Bhi  = (f16*)wp;            wp += 262144*2;          // 512 KB
  f16* Blo  = (f16*)wp;            wp += 262144*2;          // 512 KB
  float* WqeS  = (float*)wp;       wp += 65536*4;           // 256 KB
  float* biasP = (float*)wp;       wp += 1024*4;
  float* gsum  = (float*)wp;       wp += 8192*4;
  int* ideg  = (int*)wp;           wp += (size_t)N*4;
  int* icnt  = (int*)wp;           wp += (size_t)N*4;
  int* irow  = (int*)wp;           wp += (size_t)(N+1)*4;
  int* csr_s = (int*)wp;           wp += (size_t)E*4;
  int* csr_e = (int*)wp;           wp += (size_t)E*4;
  size_t used = (size_t)(wp - (char*)d_ws);
  if (used > ws_size) {
    leak_kernel<<<(G + 255)/256, 256, 0, stream>>>((float*)d_out, G, (float)(ws_size >> 20));
    return;
  }
  // encoder-phase aliases (dead before convs; all fit incl. 128-row pad):
  f16* EA16  = HA;                 // [E+128,16]  6.4M halves <= NPAD*256
  f16* HID   = PROJ;               // [E+128,64]  25.6M halves
  f16* EFtmp = PROJ + (size_t)E*64;// [E,64] + pad inside PROJ (NPAD*1024)

  const int* src = ei;
  const int* dst = ei + E;

  // ---- zero gsum/deg/cnt (contiguous) ----
  zero_kernel<<<(8192 + 2*N + 255)/256, 256, 0, stream>>>((int*)gsum, 8192 + 2*N);

  // ---- CSR by dst ----
  hist_kernel<<<(E + 255)/256, 256, 0, stream>>>(dst, ideg, E);
  scan_kernel<<<1, 1024, 0, stream>>>(ideg, irow, N);
  scatter_kernel<<<(E + 255)/256, 256, 0, stream>>>(src, dst, irow, icnt, csr_s, csr_e, E);

  // ---- edge encoder (fp16 MFMA): e = relu(ea@W1+b1)@W2+b2 ----
  cvt16_kernel<<<(E*16 + 255)/256, 256, 0, stream>>>(eattr, EA16, E*16);
  packB_kernel<<<(64*32 + 255)/256, 256, 0, stream>>>(ee_w1, 64, 16, 64, 0, Bhi, Blo, 32);
  launch_hgemm(stream, EA16, 16, 32, nullptr, 0, 0, Bhi, Blo, 32, ee_b1,
               HID, 64, E, 64, 1, nullptr, 0, 0,0,0,0);
  packB_kernel<<<(64*64 + 255)/256, 256, 0, stream>>>(ee_w2, 64, 64, 64, 0, Bhi, Blo, 64);
  launch_hgemm(stream, HID, 64, 64, nullptr, 0, 0, Bhi, Blo, 64, ee_b2,
               EFtmp, 64, E, 64, 0, nullptr, 0, 0,0,0,0);
  gather_ef16_kernel<<<(E*8 + 255)/256, 256, 0, stream>>>(EFtmp, csr_e, EFh, E);

  // ---- x -> fp16 (EA16 dead now) ----
  cvt16_kernel<<<(N*64 + 255)/256, 256, 0, stream>>>(x, HA, N*64);

  // ================= conv layers =================
  for (int c = 0; c < 3; ++c) {
    const int din = (c == 0) ? 64 : 256;
    const int H   = (c == 2) ? 1 : 4;
    const int hc  = H * 64;
    const int ldp = 4 * hc;
    const f16* Xin = (c == 0) ? HA : ((c == 1) ? HB : HA);
    const int  ldx = (c == 0) ? 64 : 256;
    f16* Hout = (c == 1) ? HA : HB;
    const ConvW& W = cw[c];

    // combined qwe weights + packed proj B = [Wq|Wk|Wv|Wqe], bias = [bq|bk|bv|bqe]
    wqe_kernel<<<((din+1)*hc + 255)/256, 256, 0, stream>>>(W.wq, W.bq, W.we, WqeS, biasP + 3*hc, din, H);
    int Kp = din;  // din is 64 or 256, both mult of 32
    packB_kernel<<<(hc*Kp + 255)/256, 256, 0, stream>>>(W.wq, hc, din, hc, 0,    Bhi, Blo, Kp);
    packB_kernel<<<(hc*Kp + 255)/256, 256, 0, stream>>>(W.wk, hc, din, hc, hc,   Bhi, Blo, Kp);
    packB_kernel<<<(hc*Kp + 255)/256, 256, 0, stream>>>(W.wv, hc, din, hc, 2*hc, Bhi, Blo, Kp);
    packB_kernel<<<(hc*Kp + 255)/256, 256, 0, stream>>>(WqeS, hc, din, hc, 3*hc, Bhi, Blo, Kp);
    copyf_kernel<<<(hc + 255)/256, 256, 0, stream>>>(biasP,        W.bq, hc);
    copyf_kernel<<<(hc + 255)/256, 256, 0, stream>>>(biasP + hc,   W.bk, hc);
    copyf_kernel<<<(hc + 255)/256, 256, 0, stream>>>(biasP + 2*hc, W.bv, hc);

    // fused projection: PROJ = Xin @ [Wq|Wk|Wv|Wqe] + biasP   [N, 4*hc] fp16
    launch_hgemm(stream, Xin, ldx, din, nullptr, 0, 0, Bhi, Blo, Kp, biasP,
                 PROJ, ldp, N, 4*hc, 0, nullptr, 0, 0,0,0,0);

    // aggregation (att -> Q slice, SE -> QWE slice)
    if (H == 4) agg16_kernel<256><<<(N + 3)/4,  256, 0, stream>>>(irow, csr_s, PROJ, ldp, EFh, N);
    else        agg16_kernel<64> <<<(N + 15)/16,256, 0, stream>>>(irow, csr_s, PROJ, ldp, EFh, N);

    // post: Hout = BN_ELU( [SE | Xin] @ [blockdiag(we); ws] + bs + att )
    int Kpp = hc + din;  // 320, 512, 320 -- all mult of 32
    packBpost_kernel<<<(hc*Kpp + 255)/256, 256, 0, stream>>>(W.we, W.ws, din, hc, Bhi, Blo, Kpp);
    launch_hgemm(stream, PROJ + 3*hc, ldp, hc, Xin, ldx, din, Bhi, Blo, Kpp, W.bs,
                 Hout, hc, N, hc, 2, PROJ, ldp, W.bg, W.bb, W.bm, W.bv_);
  }

  // ---- global mean pool + MLP ----
  {
    int chunks = (N + 63) / 64;
    pool16_kernel<<<(chunks + 3)/4, 256, 0, stream>>>(HB, batch, gsum, N);
  }
  mlp_kernel<<<1, 128, 0, stream>>>(gsum, batch, N, G, r_w1, r_b1, r_w2, r_b2, r_w3, r_b3,
                                    (float*)d_out);
}

// Round 7
// 854.035 us; speedup vs baseline: 2.4295x; 1.1256x over previous
//
#include <hip/hip_runtime.h>
#include <math.h>

// ---------------------------------------------------------------------------
// GTR_50139448214076: 3x TransformerConv GNN + BN/ELU + mean-pool + MLP
// All GEMMs on MFMA fp16 (PURE fp16 weights now), activations fp16, fp32 acc.
// Per conv: ONE fused projection GEMM X@[Wq|Wk|Wv|Wqe] -> PROJ[N,4*hc],
// wave-per-node online-softmax aggregation (2-deep pipelined), post GEMM
// [SE|X]@[bd(we);ws] + att + BN + ELU.
// R7: 128x128 tile (64x64/wave), no lo-split, single prep_kernel for all
//     weight packing, gload_lds + XOR swizzle, XCD-chunked block swizzle.
// ---------------------------------------------------------------------------

typedef _Float16 f16;
typedef _Float16 half8  __attribute__((ext_vector_type(8)));
typedef _Float16 half4v __attribute__((ext_vector_type(4)));
typedef float    f32x4  __attribute__((ext_vector_type(4)));

__device__ __forceinline__ void gload16(const void* g, void* l){
  __builtin_amdgcn_global_load_lds((const __attribute__((address_space(1))) void*)g,
                                   (__attribute__((address_space(3))) void*)l, 16, 0, 0);
}

// ---------------- utility ----------------
__global__ void zero_kernel(int* __restrict__ p, int n){
  int i = blockIdx.x*blockDim.x + threadIdx.x;
  if (i < n) p[i] = 0;
}
__global__ void leak_kernel(float* __restrict__ out, int n, float val){
  int i = blockIdx.x*blockDim.x + threadIdx.x;
  if (i < n) out[i] = val;
}
__global__ void cvt16_kernel(const float* __restrict__ src, f16* __restrict__ dst, int n){
  int i = blockIdx.x*blockDim.x + threadIdx.x;
  if (i < n) dst[i] = (f16)src[i];
}

// ---------------- CSR build ----------------
__global__ void hist_kernel(const int* __restrict__ dst, int* __restrict__ deg, int E){
  int i = blockIdx.x*blockDim.x + threadIdx.x;
  if (i < E) atomicAdd(&deg[dst[i]], 1);
}

__global__ __launch_bounds__(1024)
void scan_kernel(const int* __restrict__ deg, int* __restrict__ rowptr, int n){
  __shared__ int buf[1024];
  __shared__ int sbase;
  int tid = threadIdx.x;
  if (tid == 0){ sbase = 0; rowptr[0] = 0; }
  __syncthreads();
  for (int start = 0; start < n; start += 4096){
    int i0 = start + tid*4;
    int a0 = (i0+0<n)?deg[i0+0]:0;
    int a1 = (i0+1<n)?deg[i0+1]:0;
    int a2 = (i0+2<n)?deg[i0+2]:0;
    int a3 = (i0+3<n)?deg[i0+3]:0;
    int s = a0+a1+a2+a3;
    int v = s;
    buf[tid] = v;
    __syncthreads();
    for (int off=1; off<1024; off<<=1){
      int t = (tid >= off) ? buf[tid-off] : 0;
      __syncthreads();
      v += t;
      buf[tid] = v;
      __syncthreads();
    }
    int pre = sbase + v - s;
    if (i0+0 < n) rowptr[i0+1] = pre + a0;
    if (i0+1 < n) rowptr[i0+2] = pre + a0 + a1;
    if (i0+2 < n) rowptr[i0+3] = pre + a0 + a1 + a2;
    if (i0+3 < n) rowptr[i0+4] = pre + s;
    __syncthreads();
    if (tid == 1023) sbase += buf[1023];
    __syncthreads();
  }
}

__global__ void scatter_kernel(const int* __restrict__ src, const int* __restrict__ dst,
                               const int* __restrict__ rowptr, int* __restrict__ cnt,
                               int* __restrict__ csr_src, int* __restrict__ csr_eid, int E){
  int i = blockIdx.x*blockDim.x + threadIdx.x;
  if (i >= E) return;
  int d = dst[i];
  int pos = rowptr[d] + atomicAdd(&cnt[d], 1);
  csr_src[pos] = src[i];
  csr_eid[pos] = i;
}

// EFh[i] = EFt[csr_eid[i]]  (fp16 edge features -> CSR order)
__global__ void gather_ef16_kernel(const f16* __restrict__ EFt, const int* __restrict__ csr_eid,
                                   f16* __restrict__ EFh, int E){
  int i = blockIdx.x*blockDim.x + threadIdx.x;   // E*8 chunks of 8 halves
  if (i >= E*8) return;
  int e = i >> 3, j8 = (i & 7) * 8;
  *(half8*)(EFh + (size_t)e*64 + j8) = *(const half8*)(EFt + (size_t)csr_eid[e]*64 + j8);
}

// ---------------- unified weight prep ----------------
// Bpk layout (halves), B^T [col][Kp] per job:
//  [0,2048)        enc1: 64 x 32  (ee_w1, K=16 zero-padded)
//  [2048,6144)     enc2: 64 x 64  (ee_w2)
//  [6144,71680)    proj0: 1024 x 64   [wq|wk|wv|wqe], hc=256, din=64
//  [71680,333824)  proj1: 1024 x 256  hc=256, din=256
//  [333824,399360) proj2: 256 x 256   hc=64,  din=256
//  [399360,481280) post0: 256 x 320   [bd(we);ws], hc=256, din=64
//  [481280,612352) post1: 256 x 512   hc=256, din=256
//  [612352,632832) post2: 64 x 320    hc=64,  din=256
// biasAll (fp32): [0,1024) conv0 [bq|bk|bv|bqe]; [1024,2048) conv1; [2048,2304) conv2
struct PrepP {
  const float *ee_w1, *ee_w2;
  const float *wq[3], *wk[3], *wv[3], *we[3], *ws[3];
  const float *bq[3], *bk[3], *bv[3];
  f16* Bpk; float* biasAll;
};

__device__ __forceinline__ float projv(const float* wq, const float* wk, const float* wv,
                                       const float* we, int hc, int din, int x){
  int c = x / din, k = x - c*din;
  int sec = c / hc, cc = c - sec*hc;
  if (sec == 0) return wq[(size_t)k*hc + cc];
  if (sec == 1) return wk[(size_t)k*hc + cc];
  if (sec == 2) return wv[(size_t)k*hc + cc];
  int h = cc >> 6, jj = cc & 63;
  const float* q = wq + (size_t)k*hc + h*64;
  const float* w = we + (size_t)jj*hc + h*64;
  float s = 0.f;
  #pragma unroll 8
  for (int t = 0; t < 64; ++t) s += q[t]*w[t];
  return s;
}
__device__ __forceinline__ float postv(const float* we, const float* ws,
                                       int hc, int din, int x){
  int Kpp = hc + din;
  int c = x / Kpp, k = x - c*Kpp;
  if (k < hc) return ((k>>6) == (c>>6)) ? we[(size_t)(k&63)*hc + c] : 0.f;
  return ws[(size_t)(k-hc)*hc + c];
}

__global__ void prep_kernel(PrepP P){
  int id = blockIdx.x*blockDim.x + threadIdx.x;
  if (id < 632832){
    float v;
    if      (id < 2048)  { int c = id>>5, k = id&31; v = (k<16) ? P.ee_w1[k*64 + c] : 0.f; }
    else if (id < 6144)  { int x = id-2048; int c = x>>6, k = x&63; v = P.ee_w2[k*64 + c]; }
    else if (id < 71680) v = projv(P.wq[0],P.wk[0],P.wv[0],P.we[0],256,64, id-6144);
    else if (id < 333824)v = projv(P.wq[1],P.wk[1],P.wv[1],P.we[1],256,256,id-71680);
    else if (id < 399360)v = projv(P.wq[2],P.wk[2],P.wv[2],P.we[2],64, 256,id-333824);
    else if (id < 481280)v = postv(P.we[0],P.ws[0],256,64, id-399360);
    else if (id < 612352)v = postv(P.we[1],P.ws[1],256,256,id-481280);
    else                 v = postv(P.we[2],P.ws[2],64, 256,id-612352);
    P.Bpk[id] = (f16)v;
  } else if (id < 632832 + 2304){
    int x = id - 632832;
    int cv, off, hc;
    if (x < 1024){ cv = 0; off = x;        hc = 256; }
    else if (x < 2048){ cv = 1; off = x-1024; hc = 256; }
    else { cv = 2; off = x-2048; hc = 64; }
    int sec = off / hc, cc = off - sec*hc;
    float v;
    if      (sec == 0) v = P.bq[cv][cc];
    else if (sec == 1) v = P.bk[cv][cc];
    else if (sec == 2) v = P.bv[cv][cc];
    else {
      int h = cc >> 6, jj = cc & 63;
      const float* b = P.bq[cv] + h*64;
      const float* w = P.we[cv] + (size_t)jj*hc + h*64;
      v = 0.f;
      #pragma unroll 8
      for (int t = 0; t < 64; ++t) v += b[t]*w[t];
    }
    P.biasAll[x] = v;
  }
}

// ---------------- MFMA fp16 GEMM (gload_lds + XOR swizzle, 128xBN tile) -----
// C[M, Ncols] = [A1 | A2] @ Bpk + bias. Grid (Ncols/BN, ceil(M/128)).
// LDS slot (row r, chunk c) holds global chunk c ^ ((r>>2)&3), staged via
// pre-swizzled per-lane global source. A sources padded 128 rows past M.
// mode 0: +bias; 1: +bias,relu; 2: +bias +ep(f16) +BN +ELU. Output fp16.
__device__ __forceinline__ float bn_elu(float x, float g, float b, float m, float v){
  float s = g / sqrtf(v + 1e-5f);
  float y = (x - m) * s + b;
  return y > 0.f ? y : expm1f(y);
}

template<int BN>
__global__ __launch_bounds__(256)
void hgemm_kernel(const f16* __restrict__ A1, int lda1, int K1,
                  const f16* __restrict__ A2, int lda2, int K2,
                  const f16* __restrict__ Bpk, int Kp,
                  const float* __restrict__ bias,
                  f16* __restrict__ C, int ldc, int M, int mode,
                  const f16* __restrict__ ep, int ldep,
                  const float* __restrict__ bng, const float* __restrict__ bnb,
                  const float* __restrict__ bnm, const float* __restrict__ bnv)
{
  constexpr int WM = (BN == 128) ? 64 : 32;   // rows per wave
  constexpr int MF = WM / 16;
  __shared__ f16 As[128*32];
  __shared__ f16 Bs[BN*32];
  const int tid  = threadIdx.x;
  const int lane = tid & 63;
  const int wave = tid >> 6;
  const int wm   = (BN == 128) ? (wave >> 1) : wave;
  const int wn   = (BN == 128) ? (wave & 1) : 0;
  const int l15  = lane & 15;
  const int cs   = (lane >> 4) ^ ((lane >> 2) & 3);   // fragment-read chunk
  const int csl  = (lane & 3) ^ (lane >> 4);          // staging source chunk
  const int arow = lane >> 2;                         // staging row-in-group

  // XCD-chunked bijective swizzle
  const int nbx = gridDim.x;
  const int nwg = nbx * gridDim.y;
  int bid = blockIdx.y * nbx + blockIdx.x;
  {
    int q = nwg >> 3, r = nwg & 7;
    int xcd = bid & 7, idx = bid >> 3;
    bid = (xcd < r ? xcd * (q + 1) : r * (q + 1) + (xcd - r) * q) + idx;
  }
  const int row0 = (bid / nbx) * 128;
  const int col0 = (bid % nbx) * BN;

  f32x4 acc[MF*4];
  #pragma unroll
  for (int i = 0; i < MF*4; ++i){ acc[i][0]=0.f; acc[i][1]=0.f; acc[i][2]=0.f; acc[i][3]=0.f; }

  for (int k0 = 0; k0 < Kp; k0 += 32) {
    const f16* Ap; int lda, ks;
    if (k0 < K1) { Ap = A1; lda = lda1; ks = k0; }
    else         { Ap = A2; lda = lda2; ks = k0 - K1; }
    // stage A: wave handles rows [wave*32, wave*32+32)
    #pragma unroll
    for (int t = 0; t < 2; ++t) {
      int r = wave*32 + t*16 + arow;
      gload16(Ap + (size_t)(row0 + r)*lda + ks + csl*8, As + (wave*32 + t*16)*32);
    }
    // stage B
    if (BN == 128) {
      #pragma unroll
      for (int t = 0; t < 2; ++t) {
        int r = wave*32 + t*16 + arow;
        gload16(Bpk + (size_t)(col0 + r)*Kp + k0 + csl*8, Bs + (wave*32 + t*16)*32);
      }
    } else {
      int r = wave*16 + arow;
      gload16(Bpk + (size_t)(col0 + r)*Kp + k0 + csl*8, Bs + wave*16*32);
    }
    __syncthreads();

    half8 af[MF], bf[4];
    #pragma unroll
    for (int mf = 0; mf < MF; ++mf)
      af[mf] = *(const half8*)(As + (wm*WM + mf*16 + l15)*32 + cs*8);
    #pragma unroll
    for (int nf = 0; nf < 4; ++nf)
      bf[nf] = *(const half8*)(Bs + (wn*64 + nf*16 + l15)*32 + cs*8);
    #pragma unroll
    for (int mf = 0; mf < MF; ++mf)
      #pragma unroll
      for (int nf = 0; nf < 4; ++nf)
        acc[mf*4+nf] = __builtin_amdgcn_mfma_f32_16x16x32_f16(af[mf], bf[nf], acc[mf*4+nf], 0,0,0);
    __syncthreads();
  }

  // epilogue: C/D layout col=lane&15, row=(lane>>4)*4+reg
  #pragma unroll
  for (int mf = 0; mf < MF; ++mf)
    #pragma unroll
    for (int nf = 0; nf < 4; ++nf){
      int col  = col0 + wn*64 + nf*16 + l15;
      int rowb = row0 + wm*WM + mf*16 + (lane>>4)*4;
      float bi = bias ? bias[col] : 0.f;
      #pragma unroll
      for (int i = 0; i < 4; ++i){
        int row = rowb + i;
        if (row >= M) continue;
        float r = acc[mf*4+nf][i] + bi;
        if (mode == 1) r = fmaxf(r, 0.f);
        else if (mode == 2){
          r += (float)ep[(size_t)row*ldep + col];
          r = bn_elu(r, bng[col], bnb[col], bnm[col], bnv[col]);
        }
        C[(size_t)row*ldc + col] = (f16)r;
      }
    }
}

// ---------------- aggregation: online softmax, 2-deep pipelined -------------
// PROJ row layout (stride ldp = 4*HC): [Q | K | V | QWE] each HC wide.
// att overwrites Q slice, SE overwrites QWE slice (own row only).
template<int HC>
__global__ __launch_bounds__(256)
void agg16_kernel(const int* __restrict__ rowptr, const int* __restrict__ csr_src,
                  f16* __restrict__ PROJ, int ldp, const f16* __restrict__ EFh, int nNodes)
{
  int lane = threadIdx.x & 63;
  int wid = (blockIdx.x * blockDim.x + threadIdx.x) >> 6;
  int grp = lane >> 4, l16 = lane & 15;
  int node, ch;
  if (HC == 256) { node = wid;          ch = 4*lane; }
  else           { node = wid*4 + grp;  ch = 4*l16;  }
  if (node >= nNodes) return;
  f16* rowp = PROJ + (size_t)node*ldp;
  half4v qh = *(const half4v*)(rowp + ch);
  half4v wh = *(const half4v*)(rowp + 3*HC + ch);
  float q0=qh[0],q1=qh[1],q2=qh[2],q3=qh[3];
  float w0=wh[0],w1=wh[1],w2=wh[2],w3=wh[3];
  int e0 = rowptr[node], e1 = rowptr[node+1];

  float m = -INFINITY, den = 0.f;
  float avx=0.f,avy=0.f,avz=0.f,avw=0.f, aex=0.f,aey=0.f,aez=0.f,aew=0.f;

  half4v kN, vN, eN;
  if (e0 < e1) {
    const f16* srow = PROJ + (size_t)csr_src[e0]*ldp;
    kN = *(const half4v*)(srow + HC + ch);
    vN = *(const half4v*)(srow + 2*HC + ch);
    eN = *(const half4v*)(EFh + (size_t)e0*64 + 4*l16);
  }
  for (int i = e0; i < e1; ++i) {
    half4v k4 = kN, v4 = vN, e4 = eN;
    if (i + 1 < e1) {
      const f16* srow = PROJ + (size_t)csr_src[i+1]*ldp;
      kN = *(const half4v*)(srow + HC + ch);
      vN = *(const half4v*)(srow + 2*HC + ch);
      eN = *(const half4v*)(EFh + (size_t)(i+1)*64 + 4*l16);
    }
    float ex=e4[0], ey=e4[1], ez=e4[2], ew=e4[3];
    float p = q0*(float)k4[0] + q1*(float)k4[1] + q2*(float)k4[2] + q3*(float)k4[3]
            + w0*ex + w1*ey + w2*ez + w3*ew;
    p += __shfl_xor(p, 1);
    p += __shfl_xor(p, 2);
    p += __shfl_xor(p, 4);
    p += __shfl_xor(p, 8);
    float alpha = p * 0.125f;       // 1/sqrt(64)
    float mn = fmaxf(m, alpha);
    float sc = __expf(m - mn);      // -inf -> 0 on first edge
    float w  = __expf(alpha - mn);
    den = den*sc + w;
    avx = avx*sc + w*(float)v4[0]; avy = avy*sc + w*(float)v4[1];
    avz = avz*sc + w*(float)v4[2]; avw = avw*sc + w*(float)v4[3];
    aex = aex*sc + w*ex; aey = aey*sc + w*ey;
    aez = aez*sc + w*ez; aew = aew*sc + w*ew;
    m = mn;
  }
  float inv = den > 0.f ? 1.0f/den : 0.f;
  half4v o1, o2;
  o1[0]=(f16)(avx*inv); o1[1]=(f16)(avy*inv); o1[2]=(f16)(avz*inv); o1[3]=(f16)(avw*inv);
  o2[0]=(f16)(aex*inv); o2[1]=(f16)(aey*inv); o2[2]=(f16)(aez*inv); o2[3]=(f16)(aew*inv);
  *(half4v*)(rowp + ch) = o1;
  *(half4v*)(rowp + 3*HC + ch) = o2;
}

// ---------------- mean pool (batch sorted, fp16 in) ----------------
__global__ void pool16_kernel(const f16* __restrict__ Hf, const int* __restrict__ batch,
                              float* __restrict__ gsum, int nNodes){
  const int CH = 64;
  int c = threadIdx.x & 63;
  int chunk = blockIdx.x * (blockDim.x >> 6) + (threadIdx.x >> 6);
  int n0 = chunk * CH;
  if (n0 >= nNodes) return;
  int n1 = min(n0 + CH, nNodes);
  float acc = 0.f;
  int g = batch[n0];
  for (int n = n0; n < n1; ++n) {
    int gn = batch[n];
    if (gn != g) { atomicAdd(&gsum[g*64 + c], acc); acc = 0.f; g = gn; }
    acc += (float)Hf[(size_t)n*64 + c];
  }
  atomicAdd(&gsum[g*64 + c], acc);
}

// ---------------- MLP head (fp32) ----------------
__global__ void mlp_kernel(const float* __restrict__ gsum, const int* __restrict__ batch,
                           int nNodes, int G,
                           const float* __restrict__ w1, const float* __restrict__ b1,
                           const float* __restrict__ w2, const float* __restrict__ b2,
                           const float* __restrict__ w3, const float* __restrict__ b3,
                           float* __restrict__ out){
  int g = threadIdx.x;
  if (g >= G) return;
  int lo = 0, hi = nNodes;
  while (lo < hi){ int mid = (lo+hi)>>1; if (batch[mid] < g) lo = mid+1; else hi = mid; }
  int first = lo;
  lo = 0; hi = nNodes;
  while (lo < hi){ int mid = (lo+hi)>>1; if (batch[mid] < g+1) lo = mid+1; else hi = mid; }
  int cnt = lo - first;
  float invc = 1.0f / fmaxf((float)cnt, 1.0f);
  float gm[64];
  #pragma unroll
  for (int c = 0; c < 64; ++c) gm[c] = gsum[g*64 + c] * invc;
  float r1[32];
  for (int j = 0; j < 32; ++j){
    float s = b1[j];
    for (int c = 0; c < 64; ++c) s = fmaf(gm[c], w1[c*32 + j], s);
    r1[j] = fmaxf(s, 0.f);
  }
  float r2[16];
  for (int j = 0; j < 16; ++j){
    float s = b2[j];
    for (int c = 0; c < 32; ++c) s = fmaf(r1[c], w2[c*16 + j], s);
    r2[j] = fmaxf(s, 0.f);
  }
  float s = b3[0];
  for (int c = 0; c < 16; ++c) s = fmaf(r2[c], w3[c], s);
  out[g] = s;
}

// ---------------------------------------------------------------------------
template<int BN>
static inline void launch_hgemm(hipStream_t st,
    const f16* A1, int lda1, int K1, const f16* A2, int lda2, int K2,
    const f16* Bpk, int Kp, const float* bias,
    f16* C, int ldc, int M, int Ncols, int mode,
    const f16* ep, int ldep,
    const float* g, const float* b, const float* m, const float* v)
{
  dim3 grid(Ncols / BN, (M + 127) / 128, 1);
  hgemm_kernel<BN><<<grid, 256, 0, st>>>(A1, lda1, K1, A2, lda2, K2, Bpk, Kp,
                                         bias, C, ldc, M, mode, ep, ldep, g, b, m, v);
}

struct ConvW {
  const float *wq,*bq,*wk,*bk,*wv,*bv,*we,*ws,*bs,*bg,*bb,*bm,*bv_;
};

extern "C" void kernel_launch(void* const* d_in, const int* in_sizes, int n_in,
                              void* d_out, int out_size, void* d_ws, size_t ws_size,
                              hipStream_t stream) {
  (void)n_in;
  const float* x     = (const float*)d_in[0];
  const int*   ei    = (const int*)d_in[1];
  const float* eattr = (const float*)d_in[2];
  const int*   batch = (const int*)d_in[3];
  const float* ee_w1 = (const float*)d_in[4];
  const float* ee_b1 = (const float*)d_in[5];
  const float* ee_w2 = (const float*)d_in[6];
  const float* ee_b2 = (const float*)d_in[7];
  ConvW cw[3];
  {
    int t = 8;
    for (int c = 0; c < 3; ++c){
      cw[c].wq=(const float*)d_in[t++]; cw[c].bq=(const float*)d_in[t++];
      cw[c].wk=(const float*)d_in[t++]; cw[c].bk=(const float*)d_in[t++];
      cw[c].wv=(const float*)d_in[t++]; cw[c].bv=(const float*)d_in[t++];
      cw[c].we=(const float*)d_in[t++]; cw[c].ws=(const float*)d_in[t++]; cw[c].bs=(const float*)d_in[t++];
    }
    for (int c = 0; c < 3; ++c){
      cw[c].bg=(const float*)d_in[t++]; cw[c].bb=(const float*)d_in[t++];
      cw[c].bm=(const float*)d_in[t++]; cw[c].bv_=(const float*)d_in[t++];
    }
  }
  const float* r_w1 = (const float*)d_in[47];
  const float* r_b1 = (const float*)d_in[48];
  const float* r_w2 = (const float*)d_in[49];
  const float* r_b2 = (const float*)d_in[50];
  const float* r_w3 = (const float*)d_in[51];
  const float* r_b3 = (const float*)d_in[52];

  const int N = in_sizes[0] / 64;      // 50000
  const int E = in_sizes[2] / 16;      // 400000
  const int G = out_size;              // 128

  // ---- workspace layout (A-source buffers padded 128 rows for gload) ----
  const size_t NPAD = (size_t)N + 128;
  char* wp = (char*)d_ws;
  f16* HA   = (f16*)wp;            wp += NPAD*256*2;
  f16* HB   = (f16*)wp;            wp += NPAD*256*2;
  f16* PROJ = (f16*)wp;            wp += NPAD*1024*2;
  f16* EFh  = (f16*)wp;            wp += (size_t)E*64*2;
  f16* Bpk  = (f16*)wp;            wp += 632832*2;
  float* biasAll = (float*)wp;     wp += 2304*4;
  float* gsum    = (float*)wp;     wp += 8192*4;
  int* ideg  = (int*)wp;           wp += (size_t)N*4;
  int* icnt  = (int*)wp;           wp += (size_t)N*4;
  int* irow  = (int*)wp;           wp += (size_t)(N+1)*4;
  int* csr_s = (int*)wp;           wp += (size_t)E*4;
  int* csr_e = (int*)wp;           wp += (size_t)E*4;
  size_t used = (size_t)(wp - (char*)d_ws);
  if (used > ws_size) {
    leak_kernel<<<(G + 255)/256, 256, 0, stream>>>((float*)d_out, G, (float)(ws_size >> 20));
    return;
  }
  // encoder-phase aliases (dead before convs):
  f16* EA16  = HA;                  // [E+pad,16]
  f16* HID   = PROJ;                // [E+pad,64]
  f16* EFtmp = PROJ + (size_t)E*64; // [E,64] (+pad inside PROJ)

  const int* src = ei;
  const int* dst = ei + E;

  // Bpk job offsets
  const int BO_E1 = 0, BO_E2 = 2048, BO_P0 = 6144, BO_P1 = 71680, BO_P2 = 333824;
  const int BO_S0 = 399360, BO_S1 = 481280, BO_S2 = 612352;

  // ---- weight prep (single kernel) ----
  PrepP P;
  P.ee_w1 = ee_w1; P.ee_w2 = ee_w2;
  for (int c = 0; c < 3; ++c){
    P.wq[c]=cw[c].wq; P.wk[c]=cw[c].wk; P.wv[c]=cw[c].wv; P.we[c]=cw[c].we; P.ws[c]=cw[c].ws;
    P.bq[c]=cw[c].bq; P.bk[c]=cw[c].bk; P.bv[c]=cw[c].bv;
  }
  P.Bpk = Bpk; P.biasAll = biasAll;
  prep_kernel<<<(632832 + 2304 + 255)/256, 256, 0, stream>>>(P);

  // ---- zero gsum/deg/cnt (contiguous) ----
  zero_kernel<<<(8192 + 2*N + 255)/256, 256, 0, stream>>>((int*)gsum, 8192 + 2*N);

  // ---- CSR by dst ----
  hist_kernel<<<(E + 255)/256, 256, 0, stream>>>(dst, ideg, E);
  scan_kernel<<<1, 1024, 0, stream>>>(ideg, irow, N);
  scatter_kernel<<<(E + 255)/256, 256, 0, stream>>>(src, dst, irow, icnt, csr_s, csr_e, E);

  // ---- edge encoder: e = relu(ea@W1+b1)@W2+b2 ----
  cvt16_kernel<<<(E*16 + 255)/256, 256, 0, stream>>>(eattr, EA16, E*16);
  launch_hgemm<64>(stream, EA16, 16, 32, nullptr, 0, 0, Bpk + BO_E1, 32, ee_b1,
                   HID, 64, E, 64, 1, nullptr, 0, 0,0,0,0);
  launch_hgemm<64>(stream, HID, 64, 64, nullptr, 0, 0, Bpk + BO_E2, 64, ee_b2,
                   EFtmp, 64, E, 64, 0, nullptr, 0, 0,0,0,0);
  gather_ef16_kernel<<<(E*8 + 255)/256, 256, 0, stream>>>(EFtmp, csr_e, EFh, E);

  // ---- x -> fp16 (EA16 dead now) ----
  cvt16_kernel<<<(N*64 + 255)/256, 256, 0, stream>>>(x, HA, N*64);

  // ================= conv layers =================
  const int BO_P[3] = {BO_P0, BO_P1, BO_P2};
  const int BO_S[3] = {BO_S0, BO_S1, BO_S2};
  const int bOff[3] = {0, 1024, 2048};
  for (int c = 0; c < 3; ++c) {
    const int din = (c == 0) ? 64 : 256;
    const int H   = (c == 2) ? 1 : 4;
    const int hc  = H * 64;
    const int ldp = 4 * hc;
    const f16* Xin = (c == 0) ? HA : ((c == 1) ? HB : HA);
    const int  ldx = (c == 0) ? 64 : 256;
    f16* Hout = (c == 1) ? HA : HB;
    const ConvW& W = cw[c];

    // fused projection: PROJ = Xin @ [Wq|Wk|Wv|Wqe] + bias   [N, 4*hc]
    launch_hgemm<128>(stream, Xin, ldx, din, nullptr, 0, 0, Bpk + BO_P[c], din,
                      biasAll + bOff[c], PROJ, ldp, N, 4*hc, 0, nullptr, 0, 0,0,0,0);

    // aggregation (att -> Q slice, SE -> QWE slice)
    if (H == 4) agg16_kernel<256><<<(N + 3)/4,  256, 0, stream>>>(irow, csr_s, PROJ, ldp, EFh, N);
    else        agg16_kernel<64> <<<(N + 15)/16,256, 0, stream>>>(irow, csr_s, PROJ, ldp, EFh, N);

    // post: Hout = BN_ELU( [SE | Xin] @ [bd(we); ws] + bs + att )
    int Kpp = hc + din;
    if (hc == 256)
      launch_hgemm<128>(stream, PROJ + 3*hc, ldp, hc, Xin, ldx, din, Bpk + BO_S[c], Kpp,
                        W.bs, Hout, hc, N, hc, 2, PROJ, ldp, W.bg, W.bb, W.bm, W.bv_);
    else
      launch_hgemm<64>(stream, PROJ + 3*hc, ldp, hc, Xin, ldx, din, Bpk + BO_S[c], Kpp,
                       W.bs, Hout, hc, N, hc, 2, PROJ, ldp, W.bg, W.bb, W.bm, W.bv_);
  }

  // ---- global mean pool + MLP ----
  {
    int chunks = (N + 63) / 64;
    pool16_kernel<<<(chunks + 3)/4, 256, 0, stream>>>(HB, batch, gsum, N);
  }
  mlp_kernel<<<1, 128, 0, stream>>>(gsum, batch, N, G, r_w1, r_b1, r_w2, r_b2, r_w3, r_b3,
                                    (float*)d_out);
}

// Round 8
// 790.428 us; speedup vs baseline: 2.6250x; 1.0805x over previous
//
#include <hip/hip_runtime.h>
#include <math.h>

// ---------------------------------------------------------------------------
// GTR_50139448214076: 3x TransformerConv GNN + BN/ELU + mean-pool + MLP
// All GEMMs MFMA fp16, activations fp16, fp32 acc.
// R8: PROJ stored as 4 compact planes [Q|K|V|QWE] (pstride = NPAD*hc);
//     post GEMM skips blockdiag zeros (A1 = SE plane + col0, K1=64);
//     prep kernel also does zeroing + fp32->fp16 converts (16 launches).
// ---------------------------------------------------------------------------

typedef _Float16 f16;
typedef _Float16 half8  __attribute__((ext_vector_type(8)));
typedef _Float16 half4v __attribute__((ext_vector_type(4)));
typedef float    f32x4  __attribute__((ext_vector_type(4)));

__device__ __forceinline__ void gload16(const void* g, void* l){
  __builtin_amdgcn_global_load_lds((const __attribute__((address_space(1))) void*)g,
                                   (__attribute__((address_space(3))) void*)l, 16, 0, 0);
}

// ---------------- utility ----------------
__global__ void leak_kernel(float* __restrict__ out, int n, float val){
  int i = blockIdx.x*blockDim.x + threadIdx.x;
  if (i < n) out[i] = val;
}

// ---------------- CSR build ----------------
__global__ void hist_kernel(const int* __restrict__ dst, int* __restrict__ deg, int E){
  int i = blockIdx.x*blockDim.x + threadIdx.x;
  if (i < E) atomicAdd(&deg[dst[i]], 1);
}

__global__ __launch_bounds__(1024)
void scan_kernel(const int* __restrict__ deg, int* __restrict__ rowptr, int n){
  __shared__ int buf[1024];
  __shared__ int sbase;
  int tid = threadIdx.x;
  if (tid == 0){ sbase = 0; rowptr[0] = 0; }
  __syncthreads();
  for (int start = 0; start < n; start += 4096){
    int i0 = start + tid*4;
    int a0 = (i0+0<n)?deg[i0+0]:0;
    int a1 = (i0+1<n)?deg[i0+1]:0;
    int a2 = (i0+2<n)?deg[i0+2]:0;
    int a3 = (i0+3<n)?deg[i0+3]:0;
    int s = a0+a1+a2+a3;
    int v = s;
    buf[tid] = v;
    __syncthreads();
    for (int off=1; off<1024; off<<=1){
      int t = (tid >= off) ? buf[tid-off] : 0;
      __syncthreads();
      v += t;
      buf[tid] = v;
      __syncthreads();
    }
    int pre = sbase + v - s;
    if (i0+0 < n) rowptr[i0+1] = pre + a0;
    if (i0+1 < n) rowptr[i0+2] = pre + a0 + a1;
    if (i0+2 < n) rowptr[i0+3] = pre + a0 + a1 + a2;
    if (i0+3 < n) rowptr[i0+4] = pre + s;
    __syncthreads();
    if (tid == 1023) sbase += buf[1023];
    __syncthreads();
  }
}

__global__ void scatter_kernel(const int* __restrict__ src, const int* __restrict__ dst,
                               const int* __restrict__ rowptr, int* __restrict__ cnt,
                               int* __restrict__ csr_src, int* __restrict__ csr_eid, int E){
  int i = blockIdx.x*blockDim.x + threadIdx.x;
  if (i >= E) return;
  int d = dst[i];
  int pos = rowptr[d] + atomicAdd(&cnt[d], 1);
  csr_src[pos] = src[i];
  csr_eid[pos] = i;
}

// EFh[i] = EFt[csr_eid[i]]  (fp16 edge features -> CSR order)
__global__ void gather_ef16_kernel(const f16* __restrict__ EFt, const int* __restrict__ csr_eid,
                                   f16* __restrict__ EFh, int E){
  int i = blockIdx.x*blockDim.x + threadIdx.x;   // E*8 chunks of 8 halves
  if (i >= E*8) return;
  int e = i >> 3, j8 = (i & 7) * 8;
  *(half8*)(EFh + (size_t)e*64 + j8) = *(const half8*)(EFt + (size_t)csr_eid[e]*64 + j8);
}

// ---------------- unified prep: weight pack + bias + zero + cvt ----------------
// Bpk layout (halves), B^T [col][Kp]:
//  [0,2048)        enc1: 64 x 32  (ee_w1, K=16 zero-padded)
//  [2048,6144)     enc2: 64 x 64
//  [6144,71680)    proj0: 1024 x 64   [wq|wk|wv|wqe]
//  [71680,333824)  proj1: 1024 x 256
//  [333824,399360) proj2: 256 x 256
//  [399360,432128) post0: 256 x 128   [we(compact);ws], Kpp=64+din
//  [432128,514048) post1: 256 x 320
//  [514048,534528) post2: 64 x 320
// biasAll (fp32): [0,1024) conv0 [bq|bk|bv|bqe]; [1024,2048) conv1; [2048,2304) conv2
struct PrepP {
  const float *ee_w1, *ee_w2;
  const float *wq[3], *wk[3], *wv[3], *we[3], *ws[3];
  const float *bq[3], *bk[3], *bv[3];
  f16* Bpk; float* biasAll;
  int* zeroP; int nZero;
  const float* eattr; f16* EA16; int nEA;
  const float* x; f16* XA; int nXA;
};

__device__ __forceinline__ float projv(const float* wq, const float* wk, const float* wv,
                                       const float* we, int hc, int din, int x){
  int c = x / din, k = x - c*din;
  int sec = c / hc, cc = c - sec*hc;
  if (sec == 0) return wq[(size_t)k*hc + cc];
  if (sec == 1) return wk[(size_t)k*hc + cc];
  if (sec == 2) return wv[(size_t)k*hc + cc];
  int h = cc >> 6, jj = cc & 63;
  const float* q = wq + (size_t)k*hc + h*64;
  const float* w = we + (size_t)jj*hc + h*64;
  float s = 0.f;
  #pragma unroll 8
  for (int t = 0; t < 64; ++t) s += q[t]*w[t];
  return s;
}
__device__ __forceinline__ float postv(const float* we, const float* ws,
                                       int hc, int din, int x){
  int Kpp = 64 + din;
  int c = x / Kpp, k = x - c*Kpp;
  if (k < 64) return we[(size_t)k*hc + c];
  return ws[(size_t)(k-64)*hc + c];
}

__global__ void prep_kernel(PrepP P){
  int id = blockIdx.x*blockDim.x + threadIdx.x;
  const int NB = 534528, NBB = NB + 2304;
  if (id < NB){
    float v;
    if      (id < 2048)  { int c = id>>5, k = id&31; v = (k<16) ? P.ee_w1[k*64 + c] : 0.f; }
    else if (id < 6144)  { int x = id-2048; int c = x>>6, k = x&63; v = P.ee_w2[k*64 + c]; }
    else if (id < 71680) v = projv(P.wq[0],P.wk[0],P.wv[0],P.we[0],256,64, id-6144);
    else if (id < 333824)v = projv(P.wq[1],P.wk[1],P.wv[1],P.we[1],256,256,id-71680);
    else if (id < 399360)v = projv(P.wq[2],P.wk[2],P.wv[2],P.we[2],64, 256,id-333824);
    else if (id < 432128)v = postv(P.we[0],P.ws[0],256,64, id-399360);
    else if (id < 514048)v = postv(P.we[1],P.ws[1],256,256,id-432128);
    else                 v = postv(P.we[2],P.ws[2],64, 256,id-514048);
    P.Bpk[id] = (f16)v;
  } else if (id < NBB){
    int x = id - NB;
    int cv, off, hc;
    if (x < 1024){ cv = 0; off = x;        hc = 256; }
    else if (x < 2048){ cv = 1; off = x-1024; hc = 256; }
    else { cv = 2; off = x-2048; hc = 64; }
    int sec = off / hc, cc = off - sec*hc;
    float v;
    if      (sec == 0) v = P.bq[cv][cc];
    else if (sec == 1) v = P.bk[cv][cc];
    else if (sec == 2) v = P.bv[cv][cc];
    else {
      int h = cc >> 6, jj = cc & 63;
      const float* b = P.bq[cv] + h*64;
      const float* w = P.we[cv] + (size_t)jj*hc + h*64;
      v = 0.f;
      #pragma unroll 8
      for (int t = 0; t < 64; ++t) v += b[t]*w[t];
    }
    P.biasAll[x] = v;
  } else if (id < NBB + P.nZero){
    P.zeroP[id - NBB] = 0;
  } else if (id < NBB + P.nZero + P.nEA){
    int i = id - NBB - P.nZero;
    P.EA16[i] = (f16)P.eattr[i];
  } else if (id < NBB + P.nZero + P.nEA + P.nXA){
    int i = id - NBB - P.nZero - P.nEA;
    P.XA[i] = (f16)P.x[i];
  }
}

// ---------------- MFMA fp16 GEMM (gload_lds + XOR swizzle, 128xBN tile) -----
// C = [A1 | A2] @ Bpk + bias.  Grid (Ncols/BN, ceil(M/128)).
// headOff: A1 += col0 (post GEMM per-head SE slice).
// pstride!=0: plane-split C write: C[(col>>hcShift)*pstride + row*hc + (col&hc-1)].
// mode 0: +bias; 1: +bias,relu; 2: +bias +ep(f16,ldep) +BN +ELU.
__device__ __forceinline__ float bn_elu(float x, float g, float b, float m, float v){
  float s = g / sqrtf(v + 1e-5f);
  float y = (x - m) * s + b;
  return y > 0.f ? y : expm1f(y);
}

template<int BN>
__global__ __launch_bounds__(256)
void hgemm_kernel(const f16* __restrict__ A1, int lda1, int K1,
                  const f16* __restrict__ A2, int lda2, int K2,
                  const f16* __restrict__ Bpk, int Kp,
                  const float* __restrict__ bias,
                  f16* __restrict__ C, int ldc, int M, int mode,
                  const f16* __restrict__ ep, int ldep,
                  const float* __restrict__ bng, const float* __restrict__ bnb,
                  const float* __restrict__ bnm, const float* __restrict__ bnv,
                  int headOff, size_t pstride, int hcShift)
{
  constexpr int WM = (BN == 128) ? 64 : 32;
  constexpr int MF = WM / 16;
  __shared__ f16 As[128*32];
  __shared__ f16 Bs[BN*32];
  const int tid  = threadIdx.x;
  const int lane = tid & 63;
  const int wave = tid >> 6;
  const int wm   = (BN == 128) ? (wave >> 1) : wave;
  const int wn   = (BN == 128) ? (wave & 1) : 0;
  const int l15  = lane & 15;
  const int cs   = (lane >> 4) ^ ((lane >> 2) & 3);
  const int csl  = (lane & 3) ^ (lane >> 4);
  const int arow = lane >> 2;

  // XCD-chunked bijective swizzle
  const int nbx = gridDim.x;
  const int nwg = nbx * gridDim.y;
  int bid = blockIdx.y * nbx + blockIdx.x;
  {
    int q = nwg >> 3, r = nwg & 7;
    int xcd = bid & 7, idx = bid >> 3;
    bid = (xcd < r ? xcd * (q + 1) : r * (q + 1) + (xcd - r) * q) + idx;
  }
  const int row0 = (bid / nbx) * 128;
  const int col0 = (bid % nbx) * BN;
  const f16* A1b = headOff ? (A1 + col0) : A1;

  f32x4 acc[MF*4];
  #pragma unroll
  for (int i = 0; i < MF*4; ++i){ acc[i][0]=0.f; acc[i][1]=0.f; acc[i][2]=0.f; acc[i][3]=0.f; }

  for (int k0 = 0; k0 < Kp; k0 += 32) {
    const f16* Ap; int lda, ks;
    if (k0 < K1) { Ap = A1b; lda = lda1; ks = k0; }
    else         { Ap = A2;  lda = lda2; ks = k0 - K1; }
    #pragma unroll
    for (int t = 0; t < 2; ++t) {
      int r = wave*32 + t*16 + arow;
      gload16(Ap + (size_t)(row0 + r)*lda + ks + csl*8, As + (wave*32 + t*16)*32);
    }
    if (BN == 128) {
      #pragma unroll
      for (int t = 0; t < 2; ++t) {
        int r = wave*32 + t*16 + arow;
        gload16(Bpk + (size_t)(col0 + r)*Kp + k0 + csl*8, Bs + (wave*32 + t*16)*32);
      }
    } else {
      int r = wave*16 + arow;
      gload16(Bpk + (size_t)(col0 + r)*Kp + k0 + csl*8, Bs + wave*16*32);
    }
    __syncthreads();

    half8 af[MF], bf[4];
    #pragma unroll
    for (int mf = 0; mf < MF; ++mf)
      af[mf] = *(const half8*)(As + (wm*WM + mf*16 + l15)*32 + cs*8);
    #pragma unroll
    for (int nf = 0; nf < 4; ++nf)
      bf[nf] = *(const half8*)(Bs + (wn*64 + nf*16 + l15)*32 + cs*8);
    #pragma unroll
    for (int mf = 0; mf < MF; ++mf)
      #pragma unroll
      for (int nf = 0; nf < 4; ++nf)
        acc[mf*4+nf] = __builtin_amdgcn_mfma_f32_16x16x32_f16(af[mf], bf[nf], acc[mf*4+nf], 0,0,0);
    __syncthreads();
  }

  // epilogue: C/D layout col=lane&15, row=(lane>>4)*4+reg
  #pragma unroll
  for (int mf = 0; mf < MF; ++mf)
    #pragma unroll
    for (int nf = 0; nf < 4; ++nf){
      int col  = col0 + wn*64 + nf*16 + l15;
      int rowb = row0 + wm*WM + mf*16 + (lane>>4)*4;
      float bi = bias ? bias[col] : 0.f;
      #pragma unroll
      for (int i = 0; i < 4; ++i){
        int row = rowb + i;
        if (row >= M) continue;
        float r = acc[mf*4+nf][i] + bi;
        if (mode == 1) r = fmaxf(r, 0.f);
        else if (mode == 2){
          r += (float)ep[(size_t)row*ldep + col];
          r = bn_elu(r, bng[col], bnb[col], bnm[col], bnv[col]);
        }
        if (pstride){
          int hc = 1 << hcShift;
          int plane = col >> hcShift, c2 = col & (hc - 1);
          C[(size_t)plane*pstride + (size_t)row*hc + c2] = (f16)r;
        } else {
          C[(size_t)row*ldc + col] = (f16)r;
        }
      }
    }
}

// ---------------- aggregation: online softmax, 2-deep pipelined -------------
// Planes: Q=PROJ, K=PROJ+ps, V=+2ps, QWE=+3ps; each [N,HC] compact.
// att overwrites Q plane row, SE overwrites QWE plane row.
template<int HC>
__global__ __launch_bounds__(256)
void agg16_kernel(const int* __restrict__ rowptr, const int* __restrict__ csr_src,
                  f16* __restrict__ PROJ, size_t ps, const f16* __restrict__ EFh, int nNodes)
{
  int lane = threadIdx.x & 63;
  int wid = (blockIdx.x * blockDim.x + threadIdx.x) >> 6;
  int grp = lane >> 4, l16 = lane & 15;
  int node, ch;
  if (HC == 256) { node = wid;          ch = 4*lane; }
  else           { node = wid*4 + grp;  ch = 4*l16;  }
  if (node >= nNodes) return;
  f16* Qp = PROJ;
  const f16* Kp = PROJ + ps;
  const f16* Vp = PROJ + 2*ps;
  f16* Wp = PROJ + 3*ps;
  half4v qh = *(const half4v*)(Qp + (size_t)node*HC + ch);
  half4v wh = *(const half4v*)(Wp + (size_t)node*HC + ch);
  float q0=qh[0],q1=qh[1],q2=qh[2],q3=qh[3];
  float w0=wh[0],w1=wh[1],w2=wh[2],w3=wh[3];
  int e0 = rowptr[node], e1 = rowptr[node+1];

  float m = -INFINITY, den = 0.f;
  float avx=0.f,avy=0.f,avz=0.f,avw=0.f, aex=0.f,aey=0.f,aez=0.f,aew=0.f;

  half4v kN, vN, eN;
  if (e0 < e1) {
    size_t so = (size_t)csr_src[e0]*HC + ch;
    kN = *(const half4v*)(Kp + so);
    vN = *(const half4v*)(Vp + so);
    eN = *(const half4v*)(EFh + (size_t)e0*64 + 4*l16);
  }
  for (int i = e0; i < e1; ++i) {
    half4v k4 = kN, v4 = vN, e4 = eN;
    if (i + 1 < e1) {
      size_t so = (size_t)csr_src[i+1]*HC + ch;
      kN = *(const half4v*)(Kp + so);
      vN = *(const half4v*)(Vp + so);
      eN = *(const half4v*)(EFh + (size_t)(i+1)*64 + 4*l16);
    }
    float ex=e4[0], ey=e4[1], ez=e4[2], ew=e4[3];
    float p = q0*(float)k4[0] + q1*(float)k4[1] + q2*(float)k4[2] + q3*(float)k4[3]
            + w0*ex + w1*ey + w2*ez + w3*ew;
    p += __shfl_xor(p, 1);
    p += __shfl_xor(p, 2);
    p += __shfl_xor(p, 4);
    p += __shfl_xor(p, 8);
    float alpha = p * 0.125f;       // 1/sqrt(64)
    float mn = fmaxf(m, alpha);
    float sc = __expf(m - mn);      // -inf -> 0 on first edge
    float w  = __expf(alpha - mn);
    den = den*sc + w;
    avx = avx*sc + w*(float)v4[0]; avy = avy*sc + w*(float)v4[1];
    avz = avz*sc + w*(float)v4[2]; avw = avw*sc + w*(float)v4[3];
    aex = aex*sc + w*ex; aey = aey*sc + w*ey;
    aez = aez*sc + w*ez; aew = aew*sc + w*ew;
    m = mn;
  }
  float inv = den > 0.f ? 1.0f/den : 0.f;
  half4v o1, o2;
  o1[0]=(f16)(avx*inv); o1[1]=(f16)(avy*inv); o1[2]=(f16)(avz*inv); o1[3]=(f16)(avw*inv);
  o2[0]=(f16)(aex*inv); o2[1]=(f16)(aey*inv); o2[2]=(f16)(aez*inv); o2[3]=(f16)(aew*inv);
  *(half4v*)(Qp + (size_t)node*HC + ch) = o1;
  *(half4v*)(Wp + (size_t)node*HC + ch) = o2;
}

// ---------------- mean pool (batch sorted, fp16 in) ----------------
__global__ void pool16_kernel(const f16* __restrict__ Hf, const int* __restrict__ batch,
                              float* __restrict__ gsum, int nNodes){
  const int CH = 64;
  int c = threadIdx.x & 63;
  int chunk = blockIdx.x * (blockDim.x >> 6) + (threadIdx.x >> 6);
  int n0 = chunk * CH;
  if (n0 >= nNodes) return;
  int n1 = min(n0 + CH, nNodes);
  float acc = 0.f;
  int g = batch[n0];
  for (int n = n0; n < n1; ++n) {
    int gn = batch[n];
    if (gn != g) { atomicAdd(&gsum[g*64 + c], acc); acc = 0.f; g = gn; }
    acc += (float)Hf[(size_t)n*64 + c];
  }
  atomicAdd(&gsum[g*64 + c], acc);
}

// ---------------- MLP head (fp32) ----------------
__global__ void mlp_kernel(const float* __restrict__ gsum, const int* __restrict__ batch,
                           int nNodes, int G,
                           const float* __restrict__ w1, const float* __restrict__ b1,
                           const float* __restrict__ w2, const float* __restrict__ b2,
                           const float* __restrict__ w3, const float* __restrict__ b3,
                           float* __restrict__ out){
  int g = threadIdx.x;
  if (g >= G) return;
  int lo = 0, hi = nNodes;
  while (lo < hi){ int mid = (lo+hi)>>1; if (batch[mid] < g) lo = mid+1; else hi = mid; }
  int first = lo;
  lo = 0; hi = nNodes;
  while (lo < hi){ int mid = (lo+hi)>>1; if (batch[mid] < g+1) lo = mid+1; else hi = mid; }
  int cnt = lo - first;
  float invc = 1.0f / fmaxf((float)cnt, 1.0f);
  float gm[64];
  #pragma unroll
  for (int c = 0; c < 64; ++c) gm[c] = gsum[g*64 + c] * invc;
  float r1[32];
  for (int j = 0; j < 32; ++j){
    float s = b1[j];
    for (int c = 0; c < 64; ++c) s = fmaf(gm[c], w1[c*32 + j], s);
    r1[j] = fmaxf(s, 0.f);
  }
  float r2[16];
  for (int j = 0; j < 16; ++j){
    float s = b2[j];
    for (int c = 0; c < 32; ++c) s = fmaf(r1[c], w2[c*16 + j], s);
    r2[j] = fmaxf(s, 0.f);
  }
  float s = b3[0];
  for (int c = 0; c < 16; ++c) s = fmaf(r2[c], w3[c], s);
  out[g] = s;
}

// ---------------------------------------------------------------------------
template<int BN>
static inline void launch_hgemm(hipStream_t st,
    const f16* A1, int lda1, int K1, const f16* A2, int lda2, int K2,
    const f16* Bpk, int Kp, const float* bias,
    f16* C, int ldc, int M, int Ncols, int mode,
    const f16* ep, int ldep,
    const float* g, const float* b, const float* m, const float* v,
    int headOff = 0, size_t pstride = 0, int hcShift = 0)
{
  dim3 grid(Ncols / BN, (M + 127) / 128, 1);
  hgemm_kernel<BN><<<grid, 256, 0, st>>>(A1, lda1, K1, A2, lda2, K2, Bpk, Kp,
                                         bias, C, ldc, M, mode, ep, ldep, g, b, m, v,
                                         headOff, pstride, hcShift);
}

struct ConvW {
  const float *wq,*bq,*wk,*bk,*wv,*bv,*we,*ws,*bs,*bg,*bb,*bm,*bv_;
};

extern "C" void kernel_launch(void* const* d_in, const int* in_sizes, int n_in,
                              void* d_out, int out_size, void* d_ws, size_t ws_size,
                              hipStream_t stream) {
  (void)n_in;
  const float* x     = (const float*)d_in[0];
  const int*   ei    = (const int*)d_in[1];
  const float* eattr = (const float*)d_in[2];
  const int*   batch = (const int*)d_in[3];
  const float* ee_w1 = (const float*)d_in[4];
  const float* ee_b1 = (const float*)d_in[5];
  const float* ee_w2 = (const float*)d_in[6];
  const float* ee_b2 = (const float*)d_in[7];
  ConvW cw[3];
  {
    int t = 8;
    for (int c = 0; c < 3; ++c){
      cw[c].wq=(const float*)d_in[t++]; cw[c].bq=(const float*)d_in[t++];
      cw[c].wk=(const float*)d_in[t++]; cw[c].bk=(const float*)d_in[t++];
      cw[c].wv=(const float*)d_in[t++]; cw[c].bv=(const float*)d_in[t++];
      cw[c].we=(const float*)d_in[t++]; cw[c].ws=(const float*)d_in[t++]; cw[c].bs=(const float*)d_in[t++];
    }
    for (int c = 0; c < 3; ++c){
      cw[c].bg=(const float*)d_in[t++]; cw[c].bb=(const float*)d_in[t++];
      cw[c].bm=(const float*)d_in[t++]; cw[c].bv_=(const float*)d_in[t++];
    }
  }
  const float* r_w1 = (const float*)d_in[47];
  const float* r_b1 = (const float*)d_in[48];
  const float* r_w2 = (const float*)d_in[49];
  const float* r_b2 = (const float*)d_in[50];
  const float* r_w3 = (const float*)d_in[51];
  const float* r_b3 = (const float*)d_in[52];

  const int N = in_sizes[0] / 64;      // 50000
  const int E = in_sizes[2] / 16;      // 400000
  const int G = out_size;              // 128

  // ---- workspace layout (A-source buffers padded 128 rows for gload) ----
  const size_t NPAD = (size_t)N + 128;
  char* wp = (char*)d_ws;
  f16* HA   = (f16*)wp;            wp += NPAD*256*2;
  f16* HB   = (f16*)wp;            wp += NPAD*256*2;
  f16* PROJ = (f16*)wp;            wp += NPAD*1024*2;
  f16* EFh  = (f16*)wp;            wp += (size_t)E*64*2;
  f16* Bpk  = (f16*)wp;            wp += 534528*2;
  float* biasAll = (float*)wp;     wp += 2304*4;
  float* gsum    = (float*)wp;     wp += 8192*4;
  int* ideg  = (int*)wp;           wp += (size_t)N*4;
  int* icnt  = (int*)wp;           wp += (size_t)N*4;
  int* irow  = (int*)wp;           wp += (size_t)(N+1)*4;
  int* csr_s = (int*)wp;           wp += (size_t)E*4;
  int* csr_e = (int*)wp;           wp += (size_t)E*4;
  size_t used = (size_t)(wp - (char*)d_ws);
  if (used > ws_size) {
    leak_kernel<<<(G + 255)/256, 256, 0, stream>>>((float*)d_out, G, (float)(ws_size >> 20));
    return;
  }
  // encoder-phase aliases (dead before/overwritten after use):
  f16* EA16  = HB;                  // [E,16] in HB (HB written first by conv1 post)
  f16* HID   = PROJ;                // [E,64]
  f16* EFtmp = PROJ + (size_t)E*64; // [E,64]

  const int* src = ei;
  const int* dst = ei + E;

  // Bpk job offsets
  const int BO_E1 = 0, BO_E2 = 2048, BO_P0 = 6144, BO_P1 = 71680, BO_P2 = 333824;
  const int BO_S0 = 399360, BO_S1 = 432128, BO_S2 = 514048;

  // ---- prep: weights + bias + zero(gsum/ideg/icnt) + cvt16(eattr,x) ----
  PrepP P;
  P.ee_w1 = ee_w1; P.ee_w2 = ee_w2;
  for (int c = 0; c < 3; ++c){
    P.wq[c]=cw[c].wq; P.wk[c]=cw[c].wk; P.wv[c]=cw[c].wv; P.we[c]=cw[c].we; P.ws[c]=cw[c].ws;
    P.bq[c]=cw[c].bq; P.bk[c]=cw[c].bk; P.bv[c]=cw[c].bv;
  }
  P.Bpk = Bpk; P.biasAll = biasAll;
  P.zeroP = (int*)gsum; P.nZero = 8192 + 2*N;
  P.eattr = eattr; P.EA16 = EA16; P.nEA = E*16;
  P.x = x; P.XA = HA; P.nXA = N*64;
  {
    long total = 534528 + 2304 + (long)P.nZero + P.nEA + P.nXA;
    prep_kernel<<<(int)((total + 255)/256), 256, 0, stream>>>(P);
  }

  // ---- CSR by dst ----
  hist_kernel<<<(E + 255)/256, 256, 0, stream>>>(dst, ideg, E);
  scan_kernel<<<1, 1024, 0, stream>>>(ideg, irow, N);
  scatter_kernel<<<(E + 255)/256, 256, 0, stream>>>(src, dst, irow, icnt, csr_s, csr_e, E);

  // ---- edge encoder: e = relu(ea@W1+b1)@W2+b2 ----
  launch_hgemm<64>(stream, EA16, 16, 32, nullptr, 0, 0, Bpk + BO_E1, 32, ee_b1,
                   HID, 64, E, 64, 1, nullptr, 0, 0,0,0,0);
  launch_hgemm<64>(stream, HID, 64, 64, nullptr, 0, 0, Bpk + BO_E2, 64, ee_b2,
                   EFtmp, 64, E, 64, 0, nullptr, 0, 0,0,0,0);
  gather_ef16_kernel<<<(E*8 + 255)/256, 256, 0, stream>>>(EFtmp, csr_e, EFh, E);

  // ================= conv layers =================
  const int BO_P[3] = {BO_P0, BO_P1, BO_P2};
  const int BO_S[3] = {BO_S0, BO_S1, BO_S2};
  const int bOff[3] = {0, 1024, 2048};
  for (int c = 0; c < 3; ++c) {
    const int din = (c == 0) ? 64 : 256;
    const int H   = (c == 2) ? 1 : 4;
    const int hc  = H * 64;
    const int hcShift = (hc == 256) ? 8 : 6;
    const size_t ps = NPAD * (size_t)hc;
    const f16* Xin = (c == 0) ? HA : ((c == 1) ? HB : HA);
    const int  ldx = (c == 0) ? 64 : 256;
    f16* Hout = (c == 1) ? HA : HB;
    const ConvW& W = cw[c];

    // fused projection into planes: [Q|K|V|QWE] each [N,hc]
    launch_hgemm<128>(stream, Xin, ldx, din, nullptr, 0, 0, Bpk + BO_P[c], din,
                      biasAll + bOff[c], PROJ, hc, N, 4*hc, 0, nullptr, 0, 0,0,0,0,
                      0, ps, hcShift);

    // aggregation (att -> Q plane, SE -> QWE plane)
    if (H == 4) agg16_kernel<256><<<(N + 3)/4,  256, 0, stream>>>(irow, csr_s, PROJ, ps, EFh, N);
    else        agg16_kernel<64> <<<(N + 15)/16,256, 0, stream>>>(irow, csr_s, PROJ, ps, EFh, N);

    // post: Hout = BN_ELU( SE_h@we_h + X@ws + bs + att ), Kpp = 64+din
    launch_hgemm<64>(stream, PROJ + 3*ps, hc, 64, Xin, ldx, din, Bpk + BO_S[c], 64 + din,
                     W.bs, Hout, hc, N, hc, 2, PROJ, hc, W.bg, W.bb, W.bm, W.bv_,
                     1, 0, 0);
  }

  // ---- global mean pool + MLP ----
  {
    int chunks = (N + 63) / 64;
    pool16_kernel<<<(chunks + 3)/4, 256, 0, stream>>>(HB, batch, gsum, N);
  }
  mlp_kernel<<<1, 128, 0, stream>>>(gsum, batch, N, G, r_w1, r_b1, r_w2, r_b2, r_w3, r_b3,
                                    (float*)d_out);
}